// Round 6
// baseline (1074.528 us; speedup 1.0000x reference)
//
#include <hip/hip_runtime.h>
#include <math.h>

#define BB 128
#define SS 128
#define AE 65
#define VE 65
#define TE 129
#define PFD 128
#define FUSED 545025UL
#define FUSEDI 545025
#define VSTRIDE 136            // padded w-stride (multiple of 8)
#define APLANE 8840            // 65*136
#define FPP 574976UL           // padded per-b f16 k-extent = 512*1123
#define FPPI 574976
#define KSP 512
#define CPB 16                 // chunks per pack block

// k-split halves (each a multiple of KSP=512 and 16)
#define HALF0 287744           // 562*512 ; chunks 17984 = 1124*16
#define HALF1 287232           // 561*512 ; chunks 17952 = 1122*16

typedef _Float16 half8 __attribute__((ext_vector_type(8)));
typedef float f32x16 __attribute__((ext_vector_type(16)));

// ---------------- zero-init accumulators ----------------
__global__ __launch_bounds__(256) void k_zero(float* __restrict__ p, int n) {
  int i = blockIdx.x * 256 + threadIdx.x;
  if (i < n) p[i] = 0.f;
}

// zero the pad holes of Fh: per (b,a,v) w=129..135, plus per-b tail [574600,574976)
__global__ __launch_bounds__(256) void k_fpad(_Float16* __restrict__ Fh) {
  const int b = blockIdx.x;
  _Float16* base = Fh + (size_t)b * FPP;
  for (int i = threadIdx.x; i < 29575; i += 256) {   // 65*65*7
    const int a = i / 455, r = i - a * 455;
    const int v = r / 7, e = r - v * 7;
    base[a * APLANE + v * VSTRIDE + 129 + e] = (_Float16)0.f;
  }
  for (int i = threadIdx.x; i < 376; i += 256) base[574600 + i] = (_Float16)0.f;
}

// ---------------- core: fusion[b][a][v][w], a>=1, v>=1, w=0..127 ----------------
__global__ __launch_bounds__(256) void k_core(
    const float* __restrict__ audio, const float* __restrict__ vision,
    const float* __restrict__ text, _Float16* __restrict__ Fh,
    float* __restrict__ normsq)
{
  const int b = blockIdx.x, p = blockIdx.y;
  const int tid = threadIdx.x;
  const int tw = tid & 15, tv = tid >> 4;

  __shared__ float sV[32][64];
  __shared__ float sT[32][136];
  __shared__ float sA[32][2];

  float acc[2][4][8];
#pragma unroll
  for (int aa = 0; aa < 2; ++aa)
#pragma unroll
    for (int i = 0; i < 4; ++i)
#pragma unroll
      for (int j = 0; j < 8; ++j) acc[aa][i][j] = 0.f;

  for (int c = 0; c < 4; ++c) {
    const int s0 = 32 * c;
    __syncthreads();
    const float* vb = &vision[(size_t)(b * SS + s0) * 64];
#pragma unroll
    for (int r = 0; r < 8; ++r) { const int e = tid + 256 * r; sV[e >> 6][e & 63] = vb[e]; }
    const float* tb = &text[(size_t)(b * SS + s0) * 128];
#pragma unroll
    for (int r = 0; r < 16; ++r) { const int e = tid + 256 * r; sT[e >> 7][1 + (e & 127)] = tb[e]; }
    if (tid < 32) sT[tid][0] = 1.f;
    if (tid >= 128 && tid < 192) {
      const int t2 = tid - 128, s = t2 >> 1, aa = t2 & 1;
      sA[s][aa] = audio[(size_t)(b * SS + s0 + s) * 64 + 2 * p + aa];
    }
    __syncthreads();
#pragma unroll 8
    for (int s = 0; s < 32; ++s) {
      const float2 ap = *(const float2*)&sA[s][0];
      const float4 vv = *(const float4*)&sV[s][4 * tv];
      const float4 t0 = *(const float4*)&sT[s][8 * tw];
      const float4 t1 = *(const float4*)&sT[s][8 * tw + 4];
      const float tt[8] = {t0.x, t0.y, t0.z, t0.w, t1.x, t1.y, t1.z, t1.w};
      const float vr[4] = {vv.x, vv.y, vv.z, vv.w};
#pragma unroll
      for (int i = 0; i < 4; ++i) {
        const float av0 = ap.x * vr[i];
        const float av1 = ap.y * vr[i];
#pragma unroll
        for (int j = 0; j < 8; ++j) {
          acc[0][i][j] += av0 * tt[j];
          acc[1][i][j] += av1 * tt[j];
        }
      }
    }
  }

  float ss = 0.f;
#pragma unroll
  for (int aa = 0; aa < 2; ++aa)
#pragma unroll
    for (int i = 0; i < 4; ++i)
#pragma unroll
      for (int j = 0; j < 8; ++j) ss += acc[aa][i][j] * acc[aa][i][j];
#pragma unroll
  for (int off = 32; off > 0; off >>= 1) ss += __shfl_down(ss, off);
  if ((tid & 63) == 0) atomicAdd(&normsq[b], ss);

#pragma unroll
  for (int aa = 0; aa < 2; ++aa) {
    const int a = 1 + 2 * p + aa;
    _Float16* Fb = Fh + (size_t)b * FPP + (size_t)a * APLANE;
#pragma unroll
    for (int i = 0; i < 4; ++i) {
      const int v = 1 + 4 * tv + i;
      half8 h;
#pragma unroll
      for (int j = 0; j < 8; ++j) h[j] = (_Float16)acc[aa][i][j];
      *(half8*)(Fb + (size_t)v * VSTRIDE + 8 * tw) = h;
    }
  }
}

// ---------------- plane a=0: v 0..64, w 0..128 ----------------
__global__ __launch_bounds__(256) void k_pa(
    const float* __restrict__ vision, const float* __restrict__ text,
    _Float16* __restrict__ Fh, float* __restrict__ normsq)
{
  const int b = blockIdx.x;
  const int tid = threadIdx.x;
  const int tw = tid & 15, tv = tid >> 4;
  __shared__ float sv[32][80];
  __shared__ float st[32][144];
  float acc[5][9];
#pragma unroll
  for (int i = 0; i < 5; ++i)
#pragma unroll
    for (int j = 0; j < 9; ++j) acc[i][j] = 0.f;

  for (int c = 0; c < 4; ++c) {
    const int s0 = 32 * c;
    __syncthreads();
    const float* vbase = &vision[((size_t)(b * SS + s0)) * 64];
#pragma unroll
    for (int r = 0; r < 8; ++r) {
      const int e = tid + 256 * r;
      sv[e >> 6][(e & 63) + 1] = vbase[e];
    }
    const float* tbase = &text[((size_t)(b * SS + s0)) * 128];
#pragma unroll
    for (int r = 0; r < 16; ++r) {
      const int e = tid + 256 * r;
      st[e >> 7][(e & 127) + 1] = tbase[e];
    }
    if (tid < 32) { sv[tid][0] = 1.f; st[tid][0] = 1.f; }
    __syncthreads();
    for (int s = 0; s < 32; ++s) {
      float vr[5], tr[9];
#pragma unroll
      for (int i = 0; i < 5; ++i) {
        const int vx = tv + 16 * i;
        vr[i] = (vx < VE) ? sv[s][vx] : 0.f;
      }
#pragma unroll
      for (int j = 0; j < 9; ++j) {
        const int wx = tw + 16 * j;
        tr[j] = (wx < TE) ? st[s][wx] : 0.f;
      }
#pragma unroll
      for (int i = 0; i < 5; ++i)
#pragma unroll
        for (int j = 0; j < 9; ++j) acc[i][j] += vr[i] * tr[j];
    }
  }
  _Float16* Fb = Fh + (size_t)b * FPP;   // a = 0
  float ss = 0.f;
#pragma unroll
  for (int i = 0; i < 5; ++i) {
    const int v = tv + 16 * i;
    if (v < VE) {
#pragma unroll
      for (int j = 0; j < 9; ++j) {
        const int w = tw + 16 * j;
        if (w < TE) {
          const float m = acc[i][j];
          Fb[(size_t)v * VSTRIDE + w] = (_Float16)m;
          ss += m * m;
        }
      }
    }
  }
#pragma unroll
  for (int off = 32; off > 0; off >>= 1) ss += __shfl_down(ss, off);
  if ((tid & 63) == 0) atomicAdd(&normsq[b], ss);
}

// ---------------- plane v=0: a 1..64, w 0..128 ----------------
__global__ __launch_bounds__(256) void k_pv(
    const float* __restrict__ audio, const float* __restrict__ text,
    _Float16* __restrict__ Fh, float* __restrict__ normsq)
{
  const int b = blockIdx.x;
  const int tid = threadIdx.x;
  const int tw = tid & 15, tv = tid >> 4;
  __shared__ float sa[32][64];
  __shared__ float st[32][144];
  float acc[4][9];
#pragma unroll
  for (int i = 0; i < 4; ++i)
#pragma unroll
    for (int j = 0; j < 9; ++j) acc[i][j] = 0.f;

  for (int c = 0; c < 4; ++c) {
    const int s0 = 32 * c;
    __syncthreads();
    const float* abase = &audio[((size_t)(b * SS + s0)) * 64];
#pragma unroll
    for (int r = 0; r < 8; ++r) {
      const int e = tid + 256 * r;
      sa[e >> 6][e & 63] = abase[e];
    }
    const float* tbase = &text[((size_t)(b * SS + s0)) * 128];
#pragma unroll
    for (int r = 0; r < 16; ++r) {
      const int e = tid + 256 * r;
      st[e >> 7][(e & 127) + 1] = tbase[e];
    }
    if (tid < 32) st[tid][0] = 1.f;
    __syncthreads();
    for (int s = 0; s < 32; ++s) {
      float ar[4], tr[9];
#pragma unroll
      for (int i = 0; i < 4; ++i) ar[i] = sa[s][tv + 16 * i];
#pragma unroll
      for (int j = 0; j < 9; ++j) {
        const int wx = tw + 16 * j;
        tr[j] = (wx < TE) ? st[s][wx] : 0.f;
      }
#pragma unroll
      for (int i = 0; i < 4; ++i)
#pragma unroll
        for (int j = 0; j < 9; ++j) acc[i][j] += ar[i] * tr[j];
    }
  }
  float ss = 0.f;
#pragma unroll
  for (int i = 0; i < 4; ++i) {
    const int a = 1 + tv + 16 * i;
    _Float16* Fb = Fh + (size_t)b * FPP + (size_t)a * APLANE;   // v = 0
#pragma unroll
    for (int j = 0; j < 9; ++j) {
      const int w = tw + 16 * j;
      if (w < TE) {
        const float m = acc[i][j];
        Fb[w] = (_Float16)m;
        ss += m * m;
      }
    }
  }
#pragma unroll
  for (int off = 32; off > 0; off >>= 1) ss += __shfl_down(ss, off);
  if ((tid & 63) == 0) atomicAdd(&normsq[b], ss);
}

// ---------------- column w=128: a 1..64, v 1..64 ----------------
__global__ __launch_bounds__(256) void k_wlast(
    const float* __restrict__ audio, const float* __restrict__ vision,
    const float* __restrict__ text, _Float16* __restrict__ Fh,
    float* __restrict__ Flast, float* __restrict__ normsq)
{
  const int b = blockIdx.x;
  const int tid = threadIdx.x;
  const int tw = tid & 15, tv = tid >> 4;
  __shared__ float sa[32][64];
  __shared__ float sv[32][64];
  __shared__ float swt[32];
  float acc[4][4];
#pragma unroll
  for (int i = 0; i < 4; ++i)
#pragma unroll
    for (int j = 0; j < 4; ++j) acc[i][j] = 0.f;

  for (int c = 0; c < 4; ++c) {
    const int s0 = 32 * c;
    __syncthreads();
    const float* abase = &audio[((size_t)(b * SS + s0)) * 64];
    const float* vbase = &vision[((size_t)(b * SS + s0)) * 64];
#pragma unroll
    for (int r = 0; r < 8; ++r) {
      const int e = tid + 256 * r;
      sa[e >> 6][e & 63] = abase[e];
      sv[e >> 6][e & 63] = vbase[e];
    }
    if (tid < 32) swt[tid] = text[((size_t)(b * SS + s0 + tid)) * 128 + 127];
    __syncthreads();
    for (int s = 0; s < 32; ++s) {
      const float t = swt[s];
      float ar[4], vr[4];
#pragma unroll
      for (int i = 0; i < 4; ++i) ar[i] = sa[s][tv + 16 * i] * t;
#pragma unroll
      for (int j = 0; j < 4; ++j) vr[j] = sv[s][tw + 16 * j];
#pragma unroll
      for (int i = 0; i < 4; ++i)
#pragma unroll
        for (int j = 0; j < 4; ++j) acc[i][j] += ar[i] * vr[j];
    }
  }
  float ss = 0.f;
#pragma unroll
  for (int i = 0; i < 4; ++i) {
    const int a = 1 + tv + 16 * i;
    _Float16* Fb = Fh + (size_t)b * FPP + (size_t)a * APLANE;
#pragma unroll
    for (int j = 0; j < 4; ++j) {
      const int v = 1 + tw + 16 * j;
      float m = acc[i][j];
      ss += m * m;
      if (a == 64 && v == 64) { Flast[b] = m; m = 0.f; }  // exact fp32 path via k_final
      Fb[(size_t)v * VSTRIDE + 128] = (_Float16)m;
    }
  }
#pragma unroll
  for (int off = 32; off > 0; off >>= 1) ss += __shfl_down(ss, off);
  if ((tid & 63) == 0) atomicAdd(&normsq[b], ss);
}

// ---------------- pack W1 -> f16 A-fragment order (padded-k space) ----------------
// W1P[chunk][ptile(4)][lane(64)][8 f16]; lane = (kh<<5)|p_local; value = W1[p][ko(pk)]
// or 0 in pad holes. Wave wv = ptile wv; per chunk the wave writes 1KB contiguous.
__global__ __launch_bounds__(256) void k_pack(
    const float* __restrict__ W1, _Float16* __restrict__ W1P, int kp_base)
{
  const int tid = threadIdx.x;
  const int wv = tid >> 6, ln = tid & 63;
  const int lb = ln & 31, hb = ln >> 5;
  const int p = (wv << 5) + lb;
  const float* wrow = W1 + (size_t)p * FUSED;
  const int c0 = blockIdx.x * CPB;

#pragma unroll 4
  for (int t = 0; t < CPB; ++t) {
    const int cl = c0 + t;
    const int pk8 = kp_base + (cl << 4) + (hb << 3);  // global padded-k of elem 0
    const int a = pk8 / APLANE;
    const int r1 = pk8 - a * APLANE;
    const int v = r1 / VSTRIDE;
    const int w = r1 - v * VSTRIDE;                   // multiple of 8: 0..128
    half8 h = {};
    if (a < 65) {
      const int ko = a * 8385 + v * 129 + w;
      if (w <= 120) {
#pragma unroll
        for (int e = 0; e < 8; ++e) h[e] = (_Float16)wrow[ko + e];
      } else {                                        // w == 128: 1 valid + 7 holes
        h[0] = (_Float16)wrow[ko];
      }
    }
    *(half8*)((char*)W1P + ((size_t)cl << 12) + (wv << 10) + (ln << 4)) = h;
  }
}

// ---------------- deep-K MFMA GEMM: fully-linear loads, no LDS, no barriers -------
// grid = HALFx/KSP blocks. 4 waves (ptile). Per step (k16): 1 A-load (1KB/wave,
// contiguous) + 4 B-loads (Fh rows) + 4 MFMA.
__global__ __launch_bounds__(256) void k_gemm(
    const _Float16* __restrict__ W1P, const _Float16* __restrict__ Fh,
    float* __restrict__ y1pre, int kp_base)
{
  const int tid = threadIdx.x;
  const int wv = tid >> 6, ln = tid & 63;
  const int lb = ln & 31, hb = ln >> 5;
  const int kp0 = kp_base + blockIdx.x * KSP;

  const char* ap = (const char*)W1P + (((size_t)blockIdx.x * 32) << 12) + (wv << 10) + (ln << 4);
  const _Float16* fb0 = Fh + (size_t)lb * FPP + kp0 + (hb << 3);
  const _Float16* fb1 = fb0 + (size_t)32 * FPP;
  const _Float16* fb2 = fb0 + (size_t)64 * FPP;
  const _Float16* fb3 = fb0 + (size_t)96 * FPP;

  f32x16 acc0 = {}, acc1 = {}, acc2 = {}, acc3 = {};

#pragma unroll 8
  for (int t = 0; t < 32; ++t) {
    const half8 af = *(const half8*)(ap + ((size_t)t << 12));
    const int off = t << 4;
    const half8 b0 = *(const half8*)(fb0 + off);
    const half8 b1 = *(const half8*)(fb1 + off);
    const half8 b2 = *(const half8*)(fb2 + off);
    const half8 b3 = *(const half8*)(fb3 + off);
    acc0 = __builtin_amdgcn_mfma_f32_32x32x16_f16(af, b0, acc0, 0, 0, 0);
    acc1 = __builtin_amdgcn_mfma_f32_32x32x16_f16(af, b1, acc1, 0, 0, 0);
    acc2 = __builtin_amdgcn_mfma_f32_32x32x16_f16(af, b2, acc2, 0, 0, 0);
    acc3 = __builtin_amdgcn_mfma_f32_32x32x16_f16(af, b3, acc3, 0, 0, 0);
  }

  // drain: C col=lane&31 (b-local), row=(reg&3)+8*(reg>>2)+4*hb (p-local)
#pragma unroll
  for (int reg = 0; reg < 16; ++reg) {
    const int prow = (reg & 3) + 8 * (reg >> 2) + 4 * hb;
    const int pp = (wv << 5) + prow;
    atomicAdd(&y1pre[(size_t)lb * PFD + pp], acc0[reg]);
    atomicAdd(&y1pre[(size_t)(32 + lb) * PFD + pp], acc1[reg]);
    atomicAdd(&y1pre[(size_t)(64 + lb) * PFD + pp], acc2[reg]);
    atomicAdd(&y1pre[(size_t)(96 + lb) * PFD + pp], acc3[reg]);
  }
}

// ---------------- finalize: MLP per batch ----------------
__global__ __launch_bounds__(128) void k_final(
    const float* __restrict__ y1pre, const float* __restrict__ b1,
    const float* __restrict__ W2, const float* __restrict__ b2,
    const float* __restrict__ W3, const float* __restrict__ b3,
    const float* __restrict__ W1, const float* __restrict__ Flast,
    float* __restrict__ out)
{
  const int b = blockIdx.x, p = threadIdx.x;
  __shared__ float y1[PFD];
  __shared__ float red[PFD];
  const float extra = W1[(size_t)p * FUSED + (FUSED - 1)] * Flast[b];
  y1[p] = fmaxf(y1pre[(size_t)b * PFD + p] + extra + b1[p], 0.f);
  __syncthreads();
  float s = b2[p];
  for (int k = 0; k < PFD; ++k) s += y1[k] * W2[p * PFD + k];
  const float y2 = fmaxf(s, 0.f);
  red[p] = y2 * W3[p];
  __syncthreads();
  for (int off = 64; off > 0; off >>= 1) {
    if (p < off) red[p] += red[p + off];
    __syncthreads();
  }
  if (p == 0) {
    const float x = red[0] + b3[0];
    out[b] = 6.f / (1.f + expf(-x)) - 3.f;
  }
}

__global__ __launch_bounds__(128) void k_reg(const float* __restrict__ normsq,
                                             float* __restrict__ out)
{
  const int t = threadIdx.x;
  __shared__ float red[BB];
  red[t] = sqrtf(normsq[t]);
  __syncthreads();
  for (int off = 64; off > 0; off >>= 1) {
    if (t < off) red[t] += red[t + off];
    __syncthreads();
  }
  // tmp = sqrt(64*64*128/128) = 64 exactly; mean over B
  if (t == 0) out[BB] = 64.f * red[0] / (float)BB;
}

extern "C" void kernel_launch(void* const* d_in, const int* in_sizes, int n_in,
                              void* d_out, int out_size, void* d_ws, size_t ws_size,
                              hipStream_t stream) {
  const float* audio  = (const float*)d_in[0];
  const float* vision = (const float*)d_in[1];
  const float* text   = (const float*)d_in[2];
  const float* W1     = (const float*)d_in[3];
  const float* b1     = (const float*)d_in[4];
  const float* W2     = (const float*)d_in[5];
  const float* b2     = (const float*)d_in[6];
  const float* W3     = (const float*)d_in[7];
  const float* b3     = (const float*)d_in[8];
  float* out = (float*)d_out;

  // ws layout (proven bound ws >= 279,183,872 B):
  // [y1pre 64KB][normsq][Flast] | Fh @131072 (147,193,856 B) | W1P @147,324,928
  // (73,662,464 B)  -> total 220,987,392 B
  float* y1pre  = (float*)d_ws;
  float* normsq = y1pre + BB * PFD;
  float* Flast  = normsq + BB;
  _Float16* Fh  = (_Float16*)((char*)d_ws + 131072);
  _Float16* W1P = (_Float16*)((char*)d_ws + 147324928);

  k_zero<<<65, 256, 0, stream>>>(y1pre, BB * PFD + 2 * BB);
  k_fpad<<<BB, 256, 0, stream>>>(Fh);

  k_core<<<dim3(BB, 32), 256, 0, stream>>>(audio, vision, text, Fh, normsq);
  k_pa<<<BB, 256, 0, stream>>>(vision, text, Fh, normsq);
  k_pv<<<BB, 256, 0, stream>>>(audio, text, Fh, normsq);
  k_wlast<<<BB, 256, 0, stream>>>(audio, vision, text, Fh, Flast, normsq);

  // half 0: padded-k [0, HALF0)
  k_pack<<<(HALF0 / 16) / CPB, 256, 0, stream>>>(W1, W1P, 0);
  k_gemm<<<HALF0 / KSP, 256, 0, stream>>>(W1P, Fh, y1pre, 0);
  // half 1: padded-k [HALF0, FPPI)
  k_pack<<<(HALF1 / 16) / CPB, 256, 0, stream>>>(W1, W1P, HALF0);
  k_gemm<<<HALF1 / KSP, 256, 0, stream>>>(W1P, Fh, y1pre, HALF0);

  k_final<<<BB, PFD, 0, stream>>>(y1pre, b1, W2, b2, W3, b3, W1, Flast, out);
  k_reg<<<1, BB, 0, stream>>>(normsq, out);
}

// Round 8
// 621.621 us; speedup vs baseline: 1.7286x; 1.7286x over previous
//
#include <hip/hip_runtime.h>
#include <math.h>

#define BB 128
#define SS 128
#define AE 65
#define VE 65
#define TE 129
#define PFD 128
#define FUSED 545025UL
#define FUSEDI 545025
#define VSTRIDE 136            // padded w-stride (multiple of 8)
#define APLANE 8840            // 65*136
#define FPP 574976UL           // padded per-b f16 k-extent = 512*1123
#define FPPI 574976
#define KSP 512
#define NBLK 1123              // FPPI / KSP

typedef _Float16 half8 __attribute__((ext_vector_type(8)));
typedef float f32x16 __attribute__((ext_vector_type(16)));

// ---------------- zero-init accumulators ----------------
__global__ __launch_bounds__(256) void k_zero(float* __restrict__ p, int n) {
  int i = blockIdx.x * 256 + threadIdx.x;
  if (i < n) p[i] = 0.f;
}

// zero the pad holes of Fh: per (b,a,v) w=129..135, plus per-b tail [574600,574976)
__global__ __launch_bounds__(256) void k_fpad(_Float16* __restrict__ Fh) {
  const int b = blockIdx.x;
  _Float16* base = Fh + (size_t)b * FPP;
  for (int i = threadIdx.x; i < 29575; i += 256) {   // 65*65*7
    const int a = i / 455, r = i - a * 455;
    const int v = r / 7, e = r - v * 7;
    base[a * APLANE + v * VSTRIDE + 129 + e] = (_Float16)0.f;
  }
  for (int i = threadIdx.x; i < 376; i += 256) base[574600 + i] = (_Float16)0.f;
}

// ---------------- core: fusion[b][a][v][w], a>=1, v>=1, w=0..127 ----------------
__global__ __launch_bounds__(256) void k_core(
    const float* __restrict__ audio, const float* __restrict__ vision,
    const float* __restrict__ text, _Float16* __restrict__ Fh,
    float* __restrict__ normsq)
{
  const int b = blockIdx.x, p = blockIdx.y;
  const int tid = threadIdx.x;
  const int tw = tid & 15, tv = tid >> 4;

  __shared__ float sV[32][64];
  __shared__ float sT[32][136];
  __shared__ float sA[32][2];

  float acc[2][4][8];
#pragma unroll
  for (int aa = 0; aa < 2; ++aa)
#pragma unroll
    for (int i = 0; i < 4; ++i)
#pragma unroll
      for (int j = 0; j < 8; ++j) acc[aa][i][j] = 0.f;

  for (int c = 0; c < 4; ++c) {
    const int s0 = 32 * c;
    __syncthreads();
    const float* vb = &vision[(size_t)(b * SS + s0) * 64];
#pragma unroll
    for (int r = 0; r < 8; ++r) { const int e = tid + 256 * r; sV[e >> 6][e & 63] = vb[e]; }
    const float* tb = &text[(size_t)(b * SS + s0) * 128];
#pragma unroll
    for (int r = 0; r < 16; ++r) { const int e = tid + 256 * r; sT[e >> 7][1 + (e & 127)] = tb[e]; }
    if (tid < 32) sT[tid][0] = 1.f;
    if (tid >= 128 && tid < 192) {
      const int t2 = tid - 128, s = t2 >> 1, aa = t2 & 1;
      sA[s][aa] = audio[(size_t)(b * SS + s0 + s) * 64 + 2 * p + aa];
    }
    __syncthreads();
#pragma unroll 8
    for (int s = 0; s < 32; ++s) {
      const float2 ap = *(const float2*)&sA[s][0];
      const float4 vv = *(const float4*)&sV[s][4 * tv];
      const float4 t0 = *(const float4*)&sT[s][8 * tw];
      const float4 t1 = *(const float4*)&sT[s][8 * tw + 4];
      const float tt[8] = {t0.x, t0.y, t0.z, t0.w, t1.x, t1.y, t1.z, t1.w};
      const float vr[4] = {vv.x, vv.y, vv.z, vv.w};
#pragma unroll
      for (int i = 0; i < 4; ++i) {
        const float av0 = ap.x * vr[i];
        const float av1 = ap.y * vr[i];
#pragma unroll
        for (int j = 0; j < 8; ++j) {
          acc[0][i][j] += av0 * tt[j];
          acc[1][i][j] += av1 * tt[j];
        }
      }
    }
  }

  float ss = 0.f;
#pragma unroll
  for (int aa = 0; aa < 2; ++aa)
#pragma unroll
    for (int i = 0; i < 4; ++i)
#pragma unroll
      for (int j = 0; j < 8; ++j) ss += acc[aa][i][j] * acc[aa][i][j];
#pragma unroll
  for (int off = 32; off > 0; off >>= 1) ss += __shfl_down(ss, off);
  if ((tid & 63) == 0) atomicAdd(&normsq[b], ss);

#pragma unroll
  for (int aa = 0; aa < 2; ++aa) {
    const int a = 1 + 2 * p + aa;
    _Float16* Fb = Fh + (size_t)b * FPP + (size_t)a * APLANE;
#pragma unroll
    for (int i = 0; i < 4; ++i) {
      const int v = 1 + 4 * tv + i;
      half8 h;
#pragma unroll
      for (int j = 0; j < 8; ++j) h[j] = (_Float16)acc[aa][i][j];
      *(half8*)(Fb + (size_t)v * VSTRIDE + 8 * tw) = h;
    }
  }
}

// ---------------- plane a=0: v 0..64, w 0..128 ----------------
__global__ __launch_bounds__(256) void k_pa(
    const float* __restrict__ vision, const float* __restrict__ text,
    _Float16* __restrict__ Fh, float* __restrict__ normsq)
{
  const int b = blockIdx.x;
  const int tid = threadIdx.x;
  const int tw = tid & 15, tv = tid >> 4;
  __shared__ float sv[32][80];
  __shared__ float st[32][144];
  float acc[5][9];
#pragma unroll
  for (int i = 0; i < 5; ++i)
#pragma unroll
    for (int j = 0; j < 9; ++j) acc[i][j] = 0.f;

  for (int c = 0; c < 4; ++c) {
    const int s0 = 32 * c;
    __syncthreads();
    const float* vbase = &vision[((size_t)(b * SS + s0)) * 64];
#pragma unroll
    for (int r = 0; r < 8; ++r) {
      const int e = tid + 256 * r;
      sv[e >> 6][(e & 63) + 1] = vbase[e];
    }
    const float* tbase = &text[((size_t)(b * SS + s0)) * 128];
#pragma unroll
    for (int r = 0; r < 16; ++r) {
      const int e = tid + 256 * r;
      st[e >> 7][(e & 127) + 1] = tbase[e];
    }
    if (tid < 32) { sv[tid][0] = 1.f; st[tid][0] = 1.f; }
    __syncthreads();
    for (int s = 0; s < 32; ++s) {
      float vr[5], tr[9];
#pragma unroll
      for (int i = 0; i < 5; ++i) {
        const int vx = tv + 16 * i;
        vr[i] = (vx < VE) ? sv[s][vx] : 0.f;
      }
#pragma unroll
      for (int j = 0; j < 9; ++j) {
        const int wx = tw + 16 * j;
        tr[j] = (wx < TE) ? st[s][wx] : 0.f;
      }
#pragma unroll
      for (int i = 0; i < 5; ++i)
#pragma unroll
        for (int j = 0; j < 9; ++j) acc[i][j] += vr[i] * tr[j];
    }
  }
  _Float16* Fb = Fh + (size_t)b * FPP;   // a = 0
  float ss = 0.f;
#pragma unroll
  for (int i = 0; i < 5; ++i) {
    const int v = tv + 16 * i;
    if (v < VE) {
#pragma unroll
      for (int j = 0; j < 9; ++j) {
        const int w = tw + 16 * j;
        if (w < TE) {
          const float m = acc[i][j];
          Fb[(size_t)v * VSTRIDE + w] = (_Float16)m;
          ss += m * m;
        }
      }
    }
  }
#pragma unroll
  for (int off = 32; off > 0; off >>= 1) ss += __shfl_down(ss, off);
  if ((tid & 63) == 0) atomicAdd(&normsq[b], ss);
}

// ---------------- plane v=0: a 1..64, w 0..128 ----------------
__global__ __launch_bounds__(256) void k_pv(
    const float* __restrict__ audio, const float* __restrict__ text,
    _Float16* __restrict__ Fh, float* __restrict__ normsq)
{
  const int b = blockIdx.x;
  const int tid = threadIdx.x;
  const int tw = tid & 15, tv = tid >> 4;
  __shared__ float sa[32][64];
  __shared__ float st[32][144];
  float acc[4][9];
#pragma unroll
  for (int i = 0; i < 4; ++i)
#pragma unroll
    for (int j = 0; j < 9; ++j) acc[i][j] = 0.f;

  for (int c = 0; c < 4; ++c) {
    const int s0 = 32 * c;
    __syncthreads();
    const float* abase = &audio[((size_t)(b * SS + s0)) * 64];
#pragma unroll
    for (int r = 0; r < 8; ++r) {
      const int e = tid + 256 * r;
      sa[e >> 6][e & 63] = abase[e];
    }
    const float* tbase = &text[((size_t)(b * SS + s0)) * 128];
#pragma unroll
    for (int r = 0; r < 16; ++r) {
      const int e = tid + 256 * r;
      st[e >> 7][(e & 127) + 1] = tbase[e];
    }
    if (tid < 32) st[tid][0] = 1.f;
    __syncthreads();
    for (int s = 0; s < 32; ++s) {
      float ar[4], tr[9];
#pragma unroll
      for (int i = 0; i < 4; ++i) ar[i] = sa[s][tv + 16 * i];
#pragma unroll
      for (int j = 0; j < 9; ++j) {
        const int wx = tw + 16 * j;
        tr[j] = (wx < TE) ? st[s][wx] : 0.f;
      }
#pragma unroll
      for (int i = 0; i < 4; ++i)
#pragma unroll
        for (int j = 0; j < 9; ++j) acc[i][j] += ar[i] * tr[j];
    }
  }
  float ss = 0.f;
#pragma unroll
  for (int i = 0; i < 4; ++i) {
    const int a = 1 + tv + 16 * i;
    _Float16* Fb = Fh + (size_t)b * FPP + (size_t)a * APLANE;   // v = 0
#pragma unroll
    for (int j = 0; j < 9; ++j) {
      const int w = tw + 16 * j;
      if (w < TE) {
        const float m = acc[i][j];
        Fb[w] = (_Float16)m;
        ss += m * m;
      }
    }
  }
#pragma unroll
  for (int off = 32; off > 0; off >>= 1) ss += __shfl_down(ss, off);
  if ((tid & 63) == 0) atomicAdd(&normsq[b], ss);
}

// ---------------- column w=128: a 1..64, v 1..64 ----------------
__global__ __launch_bounds__(256) void k_wlast(
    const float* __restrict__ audio, const float* __restrict__ vision,
    const float* __restrict__ text, _Float16* __restrict__ Fh,
    float* __restrict__ Flast, float* __restrict__ normsq)
{
  const int b = blockIdx.x;
  const int tid = threadIdx.x;
  const int tw = tid & 15, tv = tid >> 4;
  __shared__ float sa[32][64];
  __shared__ float sv[32][64];
  __shared__ float swt[32];
  float acc[4][4];
#pragma unroll
  for (int i = 0; i < 4; ++i)
#pragma unroll
    for (int j = 0; j < 4; ++j) acc[i][j] = 0.f;

  for (int c = 0; c < 4; ++c) {
    const int s0 = 32 * c;
    __syncthreads();
    const float* abase = &audio[((size_t)(b * SS + s0)) * 64];
    const float* vbase = &vision[((size_t)(b * SS + s0)) * 64];
#pragma unroll
    for (int r = 0; r < 8; ++r) {
      const int e = tid + 256 * r;
      sa[e >> 6][e & 63] = abase[e];
      sv[e >> 6][e & 63] = vbase[e];
    }
    if (tid < 32) swt[tid] = text[((size_t)(b * SS + s0 + tid)) * 128 + 127];
    __syncthreads();
    for (int s = 0; s < 32; ++s) {
      const float t = swt[s];
      float ar[4], vr[4];
#pragma unroll
      for (int i = 0; i < 4; ++i) ar[i] = sa[s][tv + 16 * i] * t;
#pragma unroll
      for (int j = 0; j < 4; ++j) vr[j] = sv[s][tw + 16 * j];
#pragma unroll
      for (int i = 0; i < 4; ++i)
#pragma unroll
        for (int j = 0; j < 4; ++j) acc[i][j] += ar[i] * vr[j];
    }
  }
  float ss = 0.f;
#pragma unroll
  for (int i = 0; i < 4; ++i) {
    const int a = 1 + tv + 16 * i;
    _Float16* Fb = Fh + (size_t)b * FPP + (size_t)a * APLANE;
#pragma unroll
    for (int j = 0; j < 4; ++j) {
      const int v = 1 + tw + 16 * j;
      float m = acc[i][j];
      ss += m * m;
      if (a == 64 && v == 64) { Flast[b] = m; m = 0.f; }  // exact fp32 path via k_final
      Fb[(size_t)v * VSTRIDE + 128] = (_Float16)m;
    }
  }
#pragma unroll
  for (int off = 32; off > 0; off >>= 1) ss += __shfl_down(ss, off);
  if ((tid & 63) == 0) atomicAdd(&normsq[b], ss);
}

// ---------------- deep-K MFMA GEMM: gather loads, NO atomics, partial stores -------
// grid 1123 (padded-K split, KSP=512 -> 16 k32-steps). 4 waves; wave wv owns p-rows
// [32wv,32wv+32), all 128 b. A: W1 f32 gather (memcpy dwordx4, 4B-aligned ok) + cvt.
// B: Fh half8 gather. Ping-pong prefetch in fixed arrays with LITERAL indices only.
// C: per-thread 64 consecutive floats -> parts[block][tid][64], coalesced.
__global__ __launch_bounds__(256) void k_gemm(
    const float* __restrict__ W1, const _Float16* __restrict__ Fh,
    float* __restrict__ parts)
{
  const int tid = threadIdx.x;
  const int wv = tid >> 6, ln = tid & 63;
  const int lb = ln & 31, hb = ln >> 5;
  const int p = (wv << 5) + lb;
  const int kp0 = blockIdx.x * KSP;
  const int kpl0 = kp0 + (hb << 3);      // lane substep-0 padded k
  const int kpl1 = kpl0 + 16;            // lane substep-1 padded k

  // padded-k -> original W1 k trackers (advance +32/step; rollover always +25)
  int a0 = kpl0 / APLANE; int r0 = kpl0 - a0 * APLANE;
  int v0 = r0 / VSTRIDE;  int w0 = r0 - v0 * VSTRIDE;
  int ko0 = a0 * 8385 + v0 * 129 + w0;
  int a1 = kpl1 / APLANE; int r1 = kpl1 - a1 * APLANE;
  int v1 = r1 / VSTRIDE;  int w1 = r1 - v1 * VSTRIDE;
  int ko1 = a1 * 8385 + v1 * 129 + w1;

  const float* wrow = W1 + (size_t)p * FUSED;
  const _Float16* fb0 = Fh + (size_t)lb * FPP + kp0 + (hb << 3);
  const _Float16* fb1 = fb0 + (size_t)32 * FPP;
  const _Float16* fb2 = fb0 + (size_t)64 * FPP;
  const _Float16* fb3 = fb0 + (size_t)96 * FPP;
  int off = 0;

  f32x16 acc0 = {}, acc1 = {}, acc2 = {}, acc3 = {};

  float4 xa0[4], xa1[4];
  half8 bq0[8], bq1[8];

  // clamp only fires where Fh==0 (tail pad / the zeroed (64,64,128) element)
#define LOADM(S)                                                           \
  {                                                                        \
    const int kc0 = (ko0 <= 545017) ? ko0 : 545008;                        \
    const int kc1 = (ko1 <= 545017) ? ko1 : 545008;                        \
    __builtin_memcpy(&xa##S[0], wrow + kc0, 16);                           \
    __builtin_memcpy(&xa##S[1], wrow + kc0 + 4, 16);                       \
    __builtin_memcpy(&xa##S[2], wrow + kc1, 16);                           \
    __builtin_memcpy(&xa##S[3], wrow + kc1 + 4, 16);                       \
    bq##S[0] = *(const half8*)(fb0 + off);                                 \
    bq##S[1] = *(const half8*)(fb0 + off + 16);                            \
    bq##S[2] = *(const half8*)(fb1 + off);                                 \
    bq##S[3] = *(const half8*)(fb1 + off + 16);                            \
    bq##S[4] = *(const half8*)(fb2 + off);                                 \
    bq##S[5] = *(const half8*)(fb2 + off + 16);                            \
    bq##S[6] = *(const half8*)(fb3 + off);                                 \
    bq##S[7] = *(const half8*)(fb3 + off + 16);                            \
    off += 32;                                                             \
    w0 += 32; if (w0 >= VSTRIDE) { w0 -= VSTRIDE; ko0 += 25; } else ko0 += 32; \
    w1 += 32; if (w1 >= VSTRIDE) { w1 -= VSTRIDE; ko1 += 25; } else ko1 += 32; \
  }

#define COMPUTE(S)                                                         \
  {                                                                        \
    half8 af0, af1;                                                        \
    af0[0] = (_Float16)xa##S[0].x; af0[1] = (_Float16)xa##S[0].y;          \
    af0[2] = (_Float16)xa##S[0].z; af0[3] = (_Float16)xa##S[0].w;          \
    af0[4] = (_Float16)xa##S[1].x; af0[5] = (_Float16)xa##S[1].y;          \
    af0[6] = (_Float16)xa##S[1].z; af0[7] = (_Float16)xa##S[1].w;          \
    af1[0] = (_Float16)xa##S[2].x; af1[1] = (_Float16)xa##S[2].y;          \
    af1[2] = (_Float16)xa##S[2].z; af1[3] = (_Float16)xa##S[2].w;          \
    af1[4] = (_Float16)xa##S[3].x; af1[5] = (_Float16)xa##S[3].y;          \
    af1[6] = (_Float16)xa##S[3].z; af1[7] = (_Float16)xa##S[3].w;          \
    acc0 = __builtin_amdgcn_mfma_f32_32x32x16_f16(af0, bq##S[0], acc0, 0, 0, 0); \
    acc0 = __builtin_amdgcn_mfma_f32_32x32x16_f16(af1, bq##S[1], acc0, 0, 0, 0); \
    acc1 = __builtin_amdgcn_mfma_f32_32x32x16_f16(af0, bq##S[2], acc1, 0, 0, 0); \
    acc1 = __builtin_amdgcn_mfma_f32_32x32x16_f16(af1, bq##S[3], acc1, 0, 0, 0); \
    acc2 = __builtin_amdgcn_mfma_f32_32x32x16_f16(af0, bq##S[4], acc2, 0, 0, 0); \
    acc2 = __builtin_amdgcn_mfma_f32_32x32x16_f16(af1, bq##S[5], acc2, 0, 0, 0); \
    acc3 = __builtin_amdgcn_mfma_f32_32x32x16_f16(af0, bq##S[6], acc3, 0, 0, 0); \
    acc3 = __builtin_amdgcn_mfma_f32_32x32x16_f16(af1, bq##S[7], acc3, 0, 0, 0); \
  }

  LOADM(0)
#pragma unroll
  for (int t = 0; t < 16; t += 2) {
    LOADM(1)
    COMPUTE(0)
    if (t + 2 < 16) LOADM(0)
    COMPUTE(1)
  }
#undef LOADM
#undef COMPUTE

  // coalesced partial store: thread's 64 floats contiguous
  f32x16* o = (f32x16*)(parts + ((size_t)blockIdx.x * 256 + tid) * 64);
  o[0] = acc0; o[1] = acc1; o[2] = acc2; o[3] = acc3;
}

// ---------------- reduce partials -> y1pre[b][p] ----------------
// grid (64, 16): x covers (T-group of 4, all R); y = slice-stride chunk.
__global__ __launch_bounds__(256) void k_red(const float* __restrict__ parts,
                                             float* __restrict__ y1pre)
{
  const int tid = threadIdx.x;
  const int T = blockIdx.x * 4 + (tid >> 6);
  const int R = tid & 63;
  float s = 0.f;
  for (int sl = blockIdx.y; sl < NBLK; sl += 16)
    s += parts[(size_t)sl * 16384 + T * 64 + R];
  const int wv2 = T >> 6, hb2 = (T >> 5) & 1, lb2 = T & 31;
  const int q = R >> 4, rg = R & 15;
  const int b = q * 32 + lb2;
  const int pp = wv2 * 32 + (rg & 3) + 8 * (rg >> 2) + 4 * hb2;
  atomicAdd(&y1pre[b * PFD + pp], s);
}

// ---------------- finalize: MLP per batch ----------------
__global__ __launch_bounds__(128) void k_final(
    const float* __restrict__ y1pre, const float* __restrict__ b1,
    const float* __restrict__ W2, const float* __restrict__ b2,
    const float* __restrict__ W3, const float* __restrict__ b3,
    const float* __restrict__ W1, const float* __restrict__ Flast,
    float* __restrict__ out)
{
  const int b = blockIdx.x, p = threadIdx.x;
  __shared__ float y1[PFD];
  __shared__ float red[PFD];
  const float extra = W1[(size_t)p * FUSED + (FUSED - 1)] * Flast[b];
  y1[p] = fmaxf(y1pre[(size_t)b * PFD + p] + extra + b1[p], 0.f);
  __syncthreads();
  float s = b2[p];
  for (int k = 0; k < PFD; ++k) s += y1[k] * W2[p * PFD + k];
  const float y2 = fmaxf(s, 0.f);
  red[p] = y2 * W3[p];
  __syncthreads();
  for (int off = 64; off > 0; off >>= 1) {
    if (p < off) red[p] += red[p + off];
    __syncthreads();
  }
  if (p == 0) {
    const float x = red[0] + b3[0];
    out[b] = 6.f / (1.f + expf(-x)) - 3.f;
  }
}

__global__ __launch_bounds__(128) void k_reg(const float* __restrict__ normsq,
                                             float* __restrict__ out)
{
  const int t = threadIdx.x;
  __shared__ float red[BB];
  red[t] = sqrtf(normsq[t]);
  __syncthreads();
  for (int off = 64; off > 0; off >>= 1) {
    if (t < off) red[t] += red[t + off];
    __syncthreads();
  }
  // tmp = sqrt(64*64*128/128) = 64 exactly; mean over B
  if (t == 0) out[BB] = 64.f * red[0] / (float)BB;
}

extern "C" void kernel_launch(void* const* d_in, const int* in_sizes, int n_in,
                              void* d_out, int out_size, void* d_ws, size_t ws_size,
                              hipStream_t stream) {
  const float* audio  = (const float*)d_in[0];
  const float* vision = (const float*)d_in[1];
  const float* text   = (const float*)d_in[2];
  const float* W1     = (const float*)d_in[3];
  const float* b1     = (const float*)d_in[4];
  const float* W2     = (const float*)d_in[5];
  const float* b2     = (const float*)d_in[6];
  const float* W3     = (const float*)d_in[7];
  const float* b3     = (const float*)d_in[8];
  float* out = (float*)d_out;

  // ws layout (proven bound ws >= 279,183,872 B):
  // [y1pre 64KB][normsq][Flast] | Fh @131072 (147,193,856 B) |
  // parts @147,324,928 (1123*64KB = 73,596,928 B) -> total 220,921,856 B
  float* y1pre  = (float*)d_ws;
  float* normsq = y1pre + BB * PFD;
  float* Flast  = normsq + BB;
  _Float16* Fh  = (_Float16*)((char*)d_ws + 131072);
  float* parts  = (float*)((char*)d_ws + 147324928);

  k_zero<<<65, 256, 0, stream>>>(y1pre, BB * PFD + 2 * BB);
  k_fpad<<<BB, 256, 0, stream>>>(Fh);

  k_core<<<dim3(BB, 32), 256, 0, stream>>>(audio, vision, text, Fh, normsq);
  k_pa<<<BB, 256, 0, stream>>>(vision, text, Fh, normsq);
  k_pv<<<BB, 256, 0, stream>>>(audio, text, Fh, normsq);
  k_wlast<<<BB, 256, 0, stream>>>(audio, vision, text, Fh, Flast, normsq);

  k_gemm<<<NBLK, 256, 0, stream>>>(W1, Fh, parts);
  k_red<<<dim3(64, 16), 256, 0, stream>>>(parts, y1pre);

  k_final<<<BB, PFD, 0, stream>>>(y1pre, b1, W2, b2, W3, b3, W1, Flast, out);
  k_reg<<<1, BB, 0, stream>>>(normsq, out);
}

// Round 9
// 614.933 us; speedup vs baseline: 1.7474x; 1.0109x over previous
//
#include <hip/hip_runtime.h>
#include <math.h>

#define BB 128
#define SS 128
#define AE 65
#define VE 65
#define TE 129
#define PFD 128
#define FUSED 545025UL
#define FUSEDI 545025
#define VSTRIDE 136            // padded w-stride (multiple of 8)
#define APLANE 8840            // 65*136
#define FPP 574976UL           // padded per-b f16 k-extent = 512*1123
#define FPPI 574976
#define KSP 512
#define NBLK 1123              // FPPI / KSP

typedef _Float16 half8 __attribute__((ext_vector_type(8)));
typedef float f32x16 __attribute__((ext_vector_type(16)));

// ---------------- zero-init accumulators ----------------
__global__ __launch_bounds__(256) void k_zero(float* __restrict__ p, int n) {
  int i = blockIdx.x * 256 + threadIdx.x;
  if (i < n) p[i] = 0.f;
}

// zero the pad holes of Fh: per (b,a,v) w=129..135, plus per-b tail [574600,574976)
__global__ __launch_bounds__(256) void k_fpad(_Float16* __restrict__ Fh) {
  const int b = blockIdx.x;
  _Float16* base = Fh + (size_t)b * FPP;
  for (int i = threadIdx.x; i < 29575; i += 256) {   // 65*65*7
    const int a = i / 455, r = i - a * 455;
    const int v = r / 7, e = r - v * 7;
    base[a * APLANE + v * VSTRIDE + 129 + e] = (_Float16)0.f;
  }
  for (int i = threadIdx.x; i < 376; i += 256) base[574600 + i] = (_Float16)0.f;
}

// ---------------- core: fusion[b][a][v][w], a>=1, v>=1, w=0..127 ----------------
__global__ __launch_bounds__(256) void k_core(
    const float* __restrict__ audio, const float* __restrict__ vision,
    const float* __restrict__ text, _Float16* __restrict__ Fh,
    float* __restrict__ normsq)
{
  const int b = blockIdx.x, p = blockIdx.y;
  const int tid = threadIdx.x;
  const int tw = tid & 15, tv = tid >> 4;

  __shared__ float sV[32][64];
  __shared__ float sT[32][136];
  __shared__ float sA[32][2];

  float acc[2][4][8];
#pragma unroll
  for (int aa = 0; aa < 2; ++aa)
#pragma unroll
    for (int i = 0; i < 4; ++i)
#pragma unroll
      for (int j = 0; j < 8; ++j) acc[aa][i][j] = 0.f;

  for (int c = 0; c < 4; ++c) {
    const int s0 = 32 * c;
    __syncthreads();
    const float* vb = &vision[(size_t)(b * SS + s0) * 64];
#pragma unroll
    for (int r = 0; r < 8; ++r) { const int e = tid + 256 * r; sV[e >> 6][e & 63] = vb[e]; }
    const float* tb = &text[(size_t)(b * SS + s0) * 128];
#pragma unroll
    for (int r = 0; r < 16; ++r) { const int e = tid + 256 * r; sT[e >> 7][1 + (e & 127)] = tb[e]; }
    if (tid < 32) sT[tid][0] = 1.f;
    if (tid >= 128 && tid < 192) {
      const int t2 = tid - 128, s = t2 >> 1, aa = t2 & 1;
      sA[s][aa] = audio[(size_t)(b * SS + s0 + s) * 64 + 2 * p + aa];
    }
    __syncthreads();
#pragma unroll 8
    for (int s = 0; s < 32; ++s) {
      const float2 ap = *(const float2*)&sA[s][0];
      const float4 vv = *(const float4*)&sV[s][4 * tv];
      const float4 t0 = *(const float4*)&sT[s][8 * tw];
      const float4 t1 = *(const float4*)&sT[s][8 * tw + 4];
      const float tt[8] = {t0.x, t0.y, t0.z, t0.w, t1.x, t1.y, t1.z, t1.w};
      const float vr[4] = {vv.x, vv.y, vv.z, vv.w};
#pragma unroll
      for (int i = 0; i < 4; ++i) {
        const float av0 = ap.x * vr[i];
        const float av1 = ap.y * vr[i];
#pragma unroll
        for (int j = 0; j < 8; ++j) {
          acc[0][i][j] += av0 * tt[j];
          acc[1][i][j] += av1 * tt[j];
        }
      }
    }
  }

  float ss = 0.f;
#pragma unroll
  for (int aa = 0; aa < 2; ++aa)
#pragma unroll
    for (int i = 0; i < 4; ++i)
#pragma unroll
      for (int j = 0; j < 8; ++j) ss += acc[aa][i][j] * acc[aa][i][j];
#pragma unroll
  for (int off = 32; off > 0; off >>= 1) ss += __shfl_down(ss, off);
  if ((tid & 63) == 0) atomicAdd(&normsq[b], ss);

#pragma unroll
  for (int aa = 0; aa < 2; ++aa) {
    const int a = 1 + 2 * p + aa;
    _Float16* Fb = Fh + (size_t)b * FPP + (size_t)a * APLANE;
#pragma unroll
    for (int i = 0; i < 4; ++i) {
      const int v = 1 + 4 * tv + i;
      half8 h;
#pragma unroll
      for (int j = 0; j < 8; ++j) h[j] = (_Float16)acc[aa][i][j];
      *(half8*)(Fb + (size_t)v * VSTRIDE + 8 * tw) = h;
    }
  }
}

// ---------------- plane a=0: v 0..64, w 0..128 ----------------
__global__ __launch_bounds__(256) void k_pa(
    const float* __restrict__ vision, const float* __restrict__ text,
    _Float16* __restrict__ Fh, float* __restrict__ normsq)
{
  const int b = blockIdx.x;
  const int tid = threadIdx.x;
  const int tw = tid & 15, tv = tid >> 4;
  __shared__ float sv[32][80];
  __shared__ float st[32][144];
  float acc[5][9];
#pragma unroll
  for (int i = 0; i < 5; ++i)
#pragma unroll
    for (int j = 0; j < 9; ++j) acc[i][j] = 0.f;

  for (int c = 0; c < 4; ++c) {
    const int s0 = 32 * c;
    __syncthreads();
    const float* vbase = &vision[((size_t)(b * SS + s0)) * 64];
#pragma unroll
    for (int r = 0; r < 8; ++r) {
      const int e = tid + 256 * r;
      sv[e >> 6][(e & 63) + 1] = vbase[e];
    }
    const float* tbase = &text[((size_t)(b * SS + s0)) * 128];
#pragma unroll
    for (int r = 0; r < 16; ++r) {
      const int e = tid + 256 * r;
      st[e >> 7][(e & 127) + 1] = tbase[e];
    }
    if (tid < 32) { sv[tid][0] = 1.f; st[tid][0] = 1.f; }
    __syncthreads();
    for (int s = 0; s < 32; ++s) {
      float vr[5], tr[9];
#pragma unroll
      for (int i = 0; i < 5; ++i) {
        const int vx = tv + 16 * i;
        vr[i] = (vx < VE) ? sv[s][vx] : 0.f;
      }
#pragma unroll
      for (int j = 0; j < 9; ++j) {
        const int wx = tw + 16 * j;
        tr[j] = (wx < TE) ? st[s][wx] : 0.f;
      }
#pragma unroll
      for (int i = 0; i < 5; ++i)
#pragma unroll
        for (int j = 0; j < 9; ++j) acc[i][j] += vr[i] * tr[j];
    }
  }
  _Float16* Fb = Fh + (size_t)b * FPP;   // a = 0
  float ss = 0.f;
#pragma unroll
  for (int i = 0; i < 5; ++i) {
    const int v = tv + 16 * i;
    if (v < VE) {
#pragma unroll
      for (int j = 0; j < 9; ++j) {
        const int w = tw + 16 * j;
        if (w < TE) {
          const float m = acc[i][j];
          Fb[(size_t)v * VSTRIDE + w] = (_Float16)m;
          ss += m * m;
        }
      }
    }
  }
#pragma unroll
  for (int off = 32; off > 0; off >>= 1) ss += __shfl_down(ss, off);
  if ((tid & 63) == 0) atomicAdd(&normsq[b], ss);
}

// ---------------- plane v=0: a 1..64, w 0..128 ----------------
__global__ __launch_bounds__(256) void k_pv(
    const float* __restrict__ audio, const float* __restrict__ text,
    _Float16* __restrict__ Fh, float* __restrict__ normsq)
{
  const int b = blockIdx.x;
  const int tid = threadIdx.x;
  const int tw = tid & 15, tv = tid >> 4;
  __shared__ float sa[32][64];
  __shared__ float st[32][144];
  float acc[4][9];
#pragma unroll
  for (int i = 0; i < 4; ++i)
#pragma unroll
    for (int j = 0; j < 9; ++j) acc[i][j] = 0.f;

  for (int c = 0; c < 4; ++c) {
    const int s0 = 32 * c;
    __syncthreads();
    const float* abase = &audio[((size_t)(b * SS + s0)) * 64];
#pragma unroll
    for (int r = 0; r < 8; ++r) {
      const int e = tid + 256 * r;
      sa[e >> 6][e & 63] = abase[e];
    }
    const float* tbase = &text[((size_t)(b * SS + s0)) * 128];
#pragma unroll
    for (int r = 0; r < 16; ++r) {
      const int e = tid + 256 * r;
      st[e >> 7][(e & 127) + 1] = tbase[e];
    }
    if (tid < 32) st[tid][0] = 1.f;
    __syncthreads();
    for (int s = 0; s < 32; ++s) {
      float ar[4], tr[9];
#pragma unroll
      for (int i = 0; i < 4; ++i) ar[i] = sa[s][tv + 16 * i];
#pragma unroll
      for (int j = 0; j < 9; ++j) {
        const int wx = tw + 16 * j;
        tr[j] = (wx < TE) ? st[s][wx] : 0.f;
      }
#pragma unroll
      for (int i = 0; i < 4; ++i)
#pragma unroll
        for (int j = 0; j < 9; ++j) acc[i][j] += ar[i] * tr[j];
    }
  }
  float ss = 0.f;
#pragma unroll
  for (int i = 0; i < 4; ++i) {
    const int a = 1 + tv + 16 * i;
    _Float16* Fb = Fh + (size_t)b * FPP + (size_t)a * APLANE;   // v = 0
#pragma unroll
    for (int j = 0; j < 9; ++j) {
      const int w = tw + 16 * j;
      if (w < TE) {
        const float m = acc[i][j];
        Fb[w] = (_Float16)m;
        ss += m * m;
      }
    }
  }
#pragma unroll
  for (int off = 32; off > 0; off >>= 1) ss += __shfl_down(ss, off);
  if ((tid & 63) == 0) atomicAdd(&normsq[b], ss);
}

// ---------------- column w=128: a 1..64, v 1..64 ----------------
__global__ __launch_bounds__(256) void k_wlast(
    const float* __restrict__ audio, const float* __restrict__ vision,
    const float* __restrict__ text, _Float16* __restrict__ Fh,
    float* __restrict__ Flast, float* __restrict__ normsq)
{
  const int b = blockIdx.x;
  const int tid = threadIdx.x;
  const int tw = tid & 15, tv = tid >> 4;
  __shared__ float sa[32][64];
  __shared__ float sv[32][64];
  __shared__ float swt[32];
  float acc[4][4];
#pragma unroll
  for (int i = 0; i < 4; ++i)
#pragma unroll
    for (int j = 0; j < 4; ++j) acc[i][j] = 0.f;

  for (int c = 0; c < 4; ++c) {
    const int s0 = 32 * c;
    __syncthreads();
    const float* abase = &audio[((size_t)(b * SS + s0)) * 64];
    const float* vbase = &vision[((size_t)(b * SS + s0)) * 64];
#pragma unroll
    for (int r = 0; r < 8; ++r) {
      const int e = tid + 256 * r;
      sa[e >> 6][e & 63] = abase[e];
      sv[e >> 6][e & 63] = vbase[e];
    }
    if (tid < 32) swt[tid] = text[((size_t)(b * SS + s0 + tid)) * 128 + 127];
    __syncthreads();
    for (int s = 0; s < 32; ++s) {
      const float t = swt[s];
      float ar[4], vr[4];
#pragma unroll
      for (int i = 0; i < 4; ++i) ar[i] = sa[s][tv + 16 * i] * t;
#pragma unroll
      for (int j = 0; j < 4; ++j) vr[j] = sv[s][tw + 16 * j];
#pragma unroll
      for (int i = 0; i < 4; ++i)
#pragma unroll
        for (int j = 0; j < 4; ++j) acc[i][j] += ar[i] * vr[j];
    }
  }
  float ss = 0.f;
#pragma unroll
  for (int i = 0; i < 4; ++i) {
    const int a = 1 + tv + 16 * i;
    _Float16* Fb = Fh + (size_t)b * FPP + (size_t)a * APLANE;
#pragma unroll
    for (int j = 0; j < 4; ++j) {
      const int v = 1 + tw + 16 * j;
      float m = acc[i][j];
      ss += m * m;
      if (a == 64 && v == 64) { Flast[b] = m; m = 0.f; }  // exact fp32 path via k_final
      Fb[(size_t)v * VSTRIDE + 128] = (_Float16)m;
    }
  }
#pragma unroll
  for (int off = 32; off > 0; off >>= 1) ss += __shfl_down(ss, off);
  if ((tid & 63) == 0) atomicAdd(&normsq[b], ss);
}

// ---------------- deep-K MFMA GEMM: depth-3 prefetch pipeline, no atomics ----------
// grid 1123 (padded-K split, KSP=512 -> 16 k32-steps). 4 waves; wave wv owns p-rows
// [32wv,32wv+32), all 128 b. A: W1 f32 gather + cvt. B: Fh half8 gather.
// Three named buffer sets (A/B/C), loads issued 3 steps ahead of consumption.
__global__ __launch_bounds__(256) void k_gemm(
    const float* __restrict__ W1, const _Float16* __restrict__ Fh,
    float* __restrict__ parts)
{
  const int tid = threadIdx.x;
  const int wv = tid >> 6, ln = tid & 63;
  const int lb = ln & 31, hb = ln >> 5;
  const int p = (wv << 5) + lb;
  const int kp0 = blockIdx.x * KSP;
  const int kpl0 = kp0 + (hb << 3);      // lane substep-0 padded k
  const int kpl1 = kpl0 + 16;            // lane substep-1 padded k

  // padded-k -> original W1 k trackers (advance +32/step; rollover +25)
  int a0 = kpl0 / APLANE; int r0 = kpl0 - a0 * APLANE;
  int v0 = r0 / VSTRIDE;  int w0 = r0 - v0 * VSTRIDE;
  int ko0 = a0 * 8385 + v0 * 129 + w0;
  int a1 = kpl1 / APLANE; int r1 = kpl1 - a1 * APLANE;
  int v1 = r1 / VSTRIDE;  int w1 = r1 - v1 * VSTRIDE;
  int ko1 = a1 * 8385 + v1 * 129 + w1;

  const float* wrow = W1 + (size_t)p * FUSED;
  const _Float16* fb0 = Fh + (size_t)lb * FPP + kp0 + (hb << 3);
  const _Float16* fb1 = fb0 + (size_t)32 * FPP;
  const _Float16* fb2 = fb0 + (size_t)64 * FPP;
  const _Float16* fb3 = fb0 + (size_t)96 * FPP;
  int off = 0;

  f32x16 acc0 = {}, acc1 = {}, acc2 = {}, acc3 = {};

  float4 xaA[4], xaB[4], xaC[4];
  half8 bqA[8], bqB[8], bqC[8];

  // clamp only fires where Fh==0 (tail pad / the zeroed (64,64,128) element)
#define LOADM(S)                                                           \
  {                                                                        \
    const int kc0 = (ko0 <= 545017) ? ko0 : 545008;                        \
    const int kc1 = (ko1 <= 545017) ? ko1 : 545008;                        \
    __builtin_memcpy(&xa##S[0], wrow + kc0, 16);                           \
    __builtin_memcpy(&xa##S[1], wrow + kc0 + 4, 16);                       \
    __builtin_memcpy(&xa##S[2], wrow + kc1, 16);                           \
    __builtin_memcpy(&xa##S[3], wrow + kc1 + 4, 16);                       \
    bq##S[0] = *(const half8*)(fb0 + off);                                 \
    bq##S[1] = *(const half8*)(fb0 + off + 16);                            \
    bq##S[2] = *(const half8*)(fb1 + off);                                 \
    bq##S[3] = *(const half8*)(fb1 + off + 16);                            \
    bq##S[4] = *(const half8*)(fb2 + off);                                 \
    bq##S[5] = *(const half8*)(fb2 + off + 16);                            \
    bq##S[6] = *(const half8*)(fb3 + off);                                 \
    bq##S[7] = *(const half8*)(fb3 + off + 16);                            \
    off += 32;                                                             \
    w0 += 32; if (w0 >= VSTRIDE) { w0 -= VSTRIDE; ko0 += 25; } else ko0 += 32; \
    w1 += 32; if (w1 >= VSTRIDE) { w1 -= VSTRIDE; ko1 += 25; } else ko1 += 32; \
  }

#define COMPUTE(S)                                                         \
  {                                                                        \
    half8 af0, af1;                                                        \
    af0[0] = (_Float16)xa##S[0].x; af0[1] = (_Float16)xa##S[0].y;          \
    af0[2] = (_Float16)xa##S[0].z; af0[3] = (_Float16)xa##S[0].w;          \
    af0[4] = (_Float16)xa##S[1].x; af0[5] = (_Float16)xa##S[1].y;          \
    af0[6] = (_Float16)xa##S[1].z; af0[7] = (_Float16)xa##S[1].w;          \
    af1[0] = (_Float16)xa##S[2].x; af1[1] = (_Float16)xa##S[2].y;          \
    af1[2] = (_Float16)xa##S[2].z; af1[3] = (_Float16)xa##S[2].w;          \
    af1[4] = (_Float16)xa##S[3].x; af1[5] = (_Float16)xa##S[3].y;          \
    af1[6] = (_Float16)xa##S[3].z; af1[7] = (_Float16)xa##S[3].w;          \
    acc0 = __builtin_amdgcn_mfma_f32_32x32x16_f16(af0, bq##S[0], acc0, 0, 0, 0); \
    acc0 = __builtin_amdgcn_mfma_f32_32x32x16_f16(af1, bq##S[1], acc0, 0, 0, 0); \
    acc1 = __builtin_amdgcn_mfma_f32_32x32x16_f16(af0, bq##S[2], acc1, 0, 0, 0); \
    acc1 = __builtin_amdgcn_mfma_f32_32x32x16_f16(af1, bq##S[3], acc1, 0, 0, 0); \
    acc2 = __builtin_amdgcn_mfma_f32_32x32x16_f16(af0, bq##S[4], acc2, 0, 0, 0); \
    acc2 = __builtin_amdgcn_mfma_f32_32x32x16_f16(af1, bq##S[5], acc2, 0, 0, 0); \
    acc3 = __builtin_amdgcn_mfma_f32_32x32x16_f16(af0, bq##S[6], acc3, 0, 0, 0); \
    acc3 = __builtin_amdgcn_mfma_f32_32x32x16_f16(af1, bq##S[7], acc3, 0, 0, 0); \
  }

  // prologue: 3 steps in flight
  LOADM(A) LOADM(B) LOADM(C)
  // steady state: compute t, issue t+3  (t = 0..15; loads for t = 3..15)
  COMPUTE(A) LOADM(A)   // t0  -> t3
  COMPUTE(B) LOADM(B)   // t1  -> t4
  COMPUTE(C) LOADM(C)   // t2  -> t5
  COMPUTE(A) LOADM(A)   // t3  -> t6
  COMPUTE(B) LOADM(B)   // t4  -> t7
  COMPUTE(C) LOADM(C)   // t5  -> t8
  COMPUTE(A) LOADM(A)   // t6  -> t9
  COMPUTE(B) LOADM(B)   // t7  -> t10
  COMPUTE(C) LOADM(C)   // t8  -> t11
  COMPUTE(A) LOADM(A)   // t9  -> t12
  COMPUTE(B) LOADM(B)   // t10 -> t13
  COMPUTE(C) LOADM(C)   // t11 -> t14
  COMPUTE(A) LOADM(A)   // t12 -> t15
  COMPUTE(B)            // t13
  COMPUTE(C)            // t14
  COMPUTE(A)            // t15
#undef LOADM
#undef COMPUTE

  // coalesced partial store: thread's 64 floats contiguous
  f32x16* o = (f32x16*)(parts + ((size_t)blockIdx.x * 256 + tid) * 64);
  o[0] = acc0; o[1] = acc1; o[2] = acc2; o[3] = acc3;
}

// ---------------- reduce partials -> y1pre[b][p] ----------------
// grid (64, 16): x covers (T-group of 4, all R); y = slice-stride chunk.
__global__ __launch_bounds__(256) void k_red(const float* __restrict__ parts,
                                             float* __restrict__ y1pre)
{
  const int tid = threadIdx.x;
  const int T = blockIdx.x * 4 + (tid >> 6);
  const int R = tid & 63;
  float s = 0.f;
  for (int sl = blockIdx.y; sl < NBLK; sl += 16)
    s += parts[(size_t)sl * 16384 + T * 64 + R];
  const int wv2 = T >> 6, hb2 = (T >> 5) & 1, lb2 = T & 31;
  const int q = R >> 4, rg = R & 15;
  const int b = q * 32 + lb2;
  const int pp = wv2 * 32 + (rg & 3) + 8 * (rg >> 2) + 4 * hb2;
  atomicAdd(&y1pre[b * PFD + pp], s);
}

// ---------------- finalize: MLP per batch ----------------
__global__ __launch_bounds__(128) void k_final(
    const float* __restrict__ y1pre, const float* __restrict__ b1,
    const float* __restrict__ W2, const float* __restrict__ b2,
    const float* __restrict__ W3, const float* __restrict__ b3,
    const float* __restrict__ W1, const float* __restrict__ Flast,
    float* __restrict__ out)
{
  const int b = blockIdx.x, p = threadIdx.x;
  __shared__ float y1[PFD];
  __shared__ float red[PFD];
  const float extra = W1[(size_t)p * FUSED + (FUSED - 1)] * Flast[b];
  y1[p] = fmaxf(y1pre[(size_t)b * PFD + p] + extra + b1[p], 0.f);
  __syncthreads();
  float s = b2[p];
  for (int k = 0; k < PFD; ++k) s += y1[k] * W2[p * PFD + k];
  const float y2 = fmaxf(s, 0.f);
  red[p] = y2 * W3[p];
  __syncthreads();
  for (int off = 64; off > 0; off >>= 1) {
    if (p < off) red[p] += red[p + off];
    __syncthreads();
  }
  if (p == 0) {
    const float x = red[0] + b3[0];
    out[b] = 6.f / (1.f + expf(-x)) - 3.f;
  }
}

__global__ __launch_bounds__(128) void k_reg(const float* __restrict__ normsq,
                                             float* __restrict__ out)
{
  const int t = threadIdx.x;
  __shared__ float red[BB];
  red[t] = sqrtf(normsq[t]);
  __syncthreads();
  for (int off = 64; off > 0; off >>= 1) {
    if (t < off) red[t] += red[t + off];
    __syncthreads();
  }
  // tmp = sqrt(64*64*128/128) = 64 exactly; mean over B
  if (t == 0) out[BB] = 64.f * red[0] / (float)BB;
}

extern "C" void kernel_launch(void* const* d_in, const int* in_sizes, int n_in,
                              void* d_out, int out_size, void* d_ws, size_t ws_size,
                              hipStream_t stream) {
  const float* audio  = (const float*)d_in[0];
  const float* vision = (const float*)d_in[1];
  const float* text   = (const float*)d_in[2];
  const float* W1     = (const float*)d_in[3];
  const float* b1     = (const float*)d_in[4];
  const float* W2     = (const float*)d_in[5];
  const float* b2     = (const float*)d_in[6];
  const float* W3     = (const float*)d_in[7];
  const float* b3     = (const float*)d_in[8];
  float* out = (float*)d_out;

  // ws layout (proven bound ws >= 279,183,872 B):
  // [y1pre 64KB][normsq][Flast] | Fh @131072 (147,193,856 B) |
  // parts @147,324,928 (1123*64KB = 73,596,928 B) -> total 220,921,856 B
  float* y1pre  = (float*)d_ws;
  float* normsq = y1pre + BB * PFD;
  float* Flast  = normsq + BB;
  _Float16* Fh  = (_Float16*)((char*)d_ws + 131072);
  float* parts  = (float*)((char*)d_ws + 147324928);

  k_zero<<<65, 256, 0, stream>>>(y1pre, BB * PFD + 2 * BB);
  k_fpad<<<BB, 256, 0, stream>>>(Fh);

  k_core<<<dim3(BB, 32), 256, 0, stream>>>(audio, vision, text, Fh, normsq);
  k_pa<<<BB, 256, 0, stream>>>(vision, text, Fh, normsq);
  k_pv<<<BB, 256, 0, stream>>>(audio, text, Fh, normsq);
  k_wlast<<<BB, 256, 0, stream>>>(audio, vision, text, Fh, Flast, normsq);

  k_gemm<<<NBLK, 256, 0, stream>>>(W1, Fh, parts);
  k_red<<<dim3(64, 16), 256, 0, stream>>>(parts, y1pre);

  k_final<<<BB, PFD, 0, stream>>>(y1pre, b1, W2, b2, W3, b3, W1, Flast, out);
  k_reg<<<1, BB, 0, stream>>>(normsq, out);
}

// Round 10
// 514.286 us; speedup vs baseline: 2.0894x; 1.1957x over previous
//
#include <hip/hip_runtime.h>
#include <math.h>

#define BB 128
#define SS 128
#define AE 65
#define VE 65
#define TE 129
#define PFD 128
#define FUSED 545025UL
#define FUSEDI 545025
#define VSTRIDE 136            // padded w-stride (multiple of 8)
#define APLANE 8840            // 65*136
#define FPP 574976UL           // padded per-b f16 k-extent = 512*1123
#define FPPI 574976
#define KSP 512
#define NBLK 1123              // FPPI / KSP

typedef _Float16 half8 __attribute__((ext_vector_type(8)));
typedef float f32x16 __attribute__((ext_vector_type(16)));

__device__ __forceinline__ void gll4(const void* g, void* l) {
  __builtin_amdgcn_global_load_lds((const __attribute__((address_space(1))) void*)g,
                                   (__attribute__((address_space(3))) void*)l, 4, 0, 0);
}
__device__ __forceinline__ void gll16(const void* g, void* l) {
  __builtin_amdgcn_global_load_lds((const __attribute__((address_space(1))) void*)g,
                                   (__attribute__((address_space(3))) void*)l, 16, 0, 0);
}

// ---------------- zero-init accumulators ----------------
__global__ __launch_bounds__(256) void k_zero(float* __restrict__ p, int n) {
  int i = blockIdx.x * 256 + threadIdx.x;
  if (i < n) p[i] = 0.f;
}

// zero the pad holes of Fh: per (b,a,v) w=129..135, plus per-b tail [574600,574976)
__global__ __launch_bounds__(256) void k_fpad(_Float16* __restrict__ Fh) {
  const int b = blockIdx.x;
  _Float16* base = Fh + (size_t)b * FPP;
  for (int i = threadIdx.x; i < 29575; i += 256) {   // 65*65*7
    const int a = i / 455, r = i - a * 455;
    const int v = r / 7, e = r - v * 7;
    base[a * APLANE + v * VSTRIDE + 129 + e] = (_Float16)0.f;
  }
  for (int i = threadIdx.x; i < 376; i += 256) base[574600 + i] = (_Float16)0.f;
}

// ---------------- core: fusion[b][a][v][w], a>=1, v>=1, w=0..127 ----------------
__global__ __launch_bounds__(256) void k_core(
    const float* __restrict__ audio, const float* __restrict__ vision,
    const float* __restrict__ text, _Float16* __restrict__ Fh,
    float* __restrict__ normsq)
{
  const int b = blockIdx.x, p = blockIdx.y;
  const int tid = threadIdx.x;
  const int tw = tid & 15, tv = tid >> 4;

  __shared__ float sV[32][64];
  __shared__ float sT[32][136];
  __shared__ float sA[32][2];

  float acc[2][4][8];
#pragma unroll
  for (int aa = 0; aa < 2; ++aa)
#pragma unroll
    for (int i = 0; i < 4; ++i)
#pragma unroll
      for (int j = 0; j < 8; ++j) acc[aa][i][j] = 0.f;

  for (int c = 0; c < 4; ++c) {
    const int s0 = 32 * c;
    __syncthreads();
    const float* vb = &vision[(size_t)(b * SS + s0) * 64];
#pragma unroll
    for (int r = 0; r < 8; ++r) { const int e = tid + 256 * r; sV[e >> 6][e & 63] = vb[e]; }
    const float* tb = &text[(size_t)(b * SS + s0) * 128];
#pragma unroll
    for (int r = 0; r < 16; ++r) { const int e = tid + 256 * r; sT[e >> 7][1 + (e & 127)] = tb[e]; }
    if (tid < 32) sT[tid][0] = 1.f;
    if (tid >= 128 && tid < 192) {
      const int t2 = tid - 128, s = t2 >> 1, aa = t2 & 1;
      sA[s][aa] = audio[(size_t)(b * SS + s0 + s) * 64 + 2 * p + aa];
    }
    __syncthreads();
#pragma unroll 8
    for (int s = 0; s < 32; ++s) {
      const float2 ap = *(const float2*)&sA[s][0];
      const float4 vv = *(const float4*)&sV[s][4 * tv];
      const float4 t0 = *(const float4*)&sT[s][8 * tw];
      const float4 t1 = *(const float4*)&sT[s][8 * tw + 4];
      const float tt[8] = {t0.x, t0.y, t0.z, t0.w, t1.x, t1.y, t1.z, t1.w};
      const float vr[4] = {vv.x, vv.y, vv.z, vv.w};
#pragma unroll
      for (int i = 0; i < 4; ++i) {
        const float av0 = ap.x * vr[i];
        const float av1 = ap.y * vr[i];
#pragma unroll
        for (int j = 0; j < 8; ++j) {
          acc[0][i][j] += av0 * tt[j];
          acc[1][i][j] += av1 * tt[j];
        }
      }
    }
  }

  float ss = 0.f;
#pragma unroll
  for (int aa = 0; aa < 2; ++aa)
#pragma unroll
    for (int i = 0; i < 4; ++i)
#pragma unroll
      for (int j = 0; j < 8; ++j) ss += acc[aa][i][j] * acc[aa][i][j];
#pragma unroll
  for (int off = 32; off > 0; off >>= 1) ss += __shfl_down(ss, off);
  if ((tid & 63) == 0) atomicAdd(&normsq[b], ss);

#pragma unroll
  for (int aa = 0; aa < 2; ++aa) {
    const int a = 1 + 2 * p + aa;
    _Float16* Fb = Fh + (size_t)b * FPP + (size_t)a * APLANE;
#pragma unroll
    for (int i = 0; i < 4; ++i) {
      const int v = 1 + 4 * tv + i;
      half8 h;
#pragma unroll
      for (int j = 0; j < 8; ++j) h[j] = (_Float16)acc[aa][i][j];
      *(half8*)(Fb + (size_t)v * VSTRIDE + 8 * tw) = h;
    }
  }
}

// ---------------- plane a=0: v 0..64, w 0..128 ----------------
__global__ __launch_bounds__(256) void k_pa(
    const float* __restrict__ vision, const float* __restrict__ text,
    _Float16* __restrict__ Fh, float* __restrict__ normsq)
{
  const int b = blockIdx.x;
  const int tid = threadIdx.x;
  const int tw = tid & 15, tv = tid >> 4;
  __shared__ float sv[32][80];
  __shared__ float st[32][144];
  float acc[5][9];
#pragma unroll
  for (int i = 0; i < 5; ++i)
#pragma unroll
    for (int j = 0; j < 9; ++j) acc[i][j] = 0.f;

  for (int c = 0; c < 4; ++c) {
    const int s0 = 32 * c;
    __syncthreads();
    const float* vbase = &vision[((size_t)(b * SS + s0)) * 64];
#pragma unroll
    for (int r = 0; r < 8; ++r) {
      const int e = tid + 256 * r;
      sv[e >> 6][(e & 63) + 1] = vbase[e];
    }
    const float* tbase = &text[((size_t)(b * SS + s0)) * 128];
#pragma unroll
    for (int r = 0; r < 16; ++r) {
      const int e = tid + 256 * r;
      st[e >> 7][(e & 127) + 1] = tbase[e];
    }
    if (tid < 32) { sv[tid][0] = 1.f; st[tid][0] = 1.f; }
    __syncthreads();
    for (int s = 0; s < 32; ++s) {
      float vr[5], tr[9];
#pragma unroll
      for (int i = 0; i < 5; ++i) {
        const int vx = tv + 16 * i;
        vr[i] = (vx < VE) ? sv[s][vx] : 0.f;
      }
#pragma unroll
      for (int j = 0; j < 9; ++j) {
        const int wx = tw + 16 * j;
        tr[j] = (wx < TE) ? st[s][wx] : 0.f;
      }
#pragma unroll
      for (int i = 0; i < 5; ++i)
#pragma unroll
        for (int j = 0; j < 9; ++j) acc[i][j] += vr[i] * tr[j];
    }
  }
  _Float16* Fb = Fh + (size_t)b * FPP;   // a = 0
  float ss = 0.f;
#pragma unroll
  for (int i = 0; i < 5; ++i) {
    const int v = tv + 16 * i;
    if (v < VE) {
#pragma unroll
      for (int j = 0; j < 9; ++j) {
        const int w = tw + 16 * j;
        if (w < TE) {
          const float m = acc[i][j];
          Fb[(size_t)v * VSTRIDE + w] = (_Float16)m;
          ss += m * m;
        }
      }
    }
  }
#pragma unroll
  for (int off = 32; off > 0; off >>= 1) ss += __shfl_down(ss, off);
  if ((tid & 63) == 0) atomicAdd(&normsq[b], ss);
}

// ---------------- plane v=0: a 1..64, w 0..128 ----------------
__global__ __launch_bounds__(256) void k_pv(
    const float* __restrict__ audio, const float* __restrict__ text,
    _Float16* __restrict__ Fh, float* __restrict__ normsq)
{
  const int b = blockIdx.x;
  const int tid = threadIdx.x;
  const int tw = tid & 15, tv = tid >> 4;
  __shared__ float sa[32][64];
  __shared__ float st[32][144];
  float acc[4][9];
#pragma unroll
  for (int i = 0; i < 4; ++i)
#pragma unroll
    for (int j = 0; j < 9; ++j) acc[i][j] = 0.f;

  for (int c = 0; c < 4; ++c) {
    const int s0 = 32 * c;
    __syncthreads();
    const float* abase = &audio[((size_t)(b * SS + s0)) * 64];
#pragma unroll
    for (int r = 0; r < 8; ++r) {
      const int e = tid + 256 * r;
      sa[e >> 6][e & 63] = abase[e];
    }
    const float* tbase = &text[((size_t)(b * SS + s0)) * 128];
#pragma unroll
    for (int r = 0; r < 16; ++r) {
      const int e = tid + 256 * r;
      st[e >> 7][(e & 127) + 1] = tbase[e];
    }
    if (tid < 32) st[tid][0] = 1.f;
    __syncthreads();
    for (int s = 0; s < 32; ++s) {
      float ar[4], tr[9];
#pragma unroll
      for (int i = 0; i < 4; ++i) ar[i] = sa[s][tv + 16 * i];
#pragma unroll
      for (int j = 0; j < 9; ++j) {
        const int wx = tw + 16 * j;
        tr[j] = (wx < TE) ? st[s][wx] : 0.f;
      }
#pragma unroll
      for (int i = 0; i < 4; ++i)
#pragma unroll
        for (int j = 0; j < 9; ++j) acc[i][j] += ar[i] * tr[j];
    }
  }
  float ss = 0.f;
#pragma unroll
  for (int i = 0; i < 4; ++i) {
    const int a = 1 + tv + 16 * i;
    _Float16* Fb = Fh + (size_t)b * FPP + (size_t)a * APLANE;   // v = 0
#pragma unroll
    for (int j = 0; j < 9; ++j) {
      const int w = tw + 16 * j;
      if (w < TE) {
        const float m = acc[i][j];
        Fb[w] = (_Float16)m;
        ss += m * m;
      }
    }
  }
#pragma unroll
  for (int off = 32; off > 0; off >>= 1) ss += __shfl_down(ss, off);
  if ((tid & 63) == 0) atomicAdd(&normsq[b], ss);
}

// ---------------- column w=128: a 1..64, v 1..64 ----------------
__global__ __launch_bounds__(256) void k_wlast(
    const float* __restrict__ audio, const float* __restrict__ vision,
    const float* __restrict__ text, _Float16* __restrict__ Fh,
    float* __restrict__ Flast, float* __restrict__ normsq)
{
  const int b = blockIdx.x;
  const int tid = threadIdx.x;
  const int tw = tid & 15, tv = tid >> 4;
  __shared__ float sa[32][64];
  __shared__ float sv[32][64];
  __shared__ float swt[32];
  float acc[4][4];
#pragma unroll
  for (int i = 0; i < 4; ++i)
#pragma unroll
    for (int j = 0; j < 4; ++j) acc[i][j] = 0.f;

  for (int c = 0; c < 4; ++c) {
    const int s0 = 32 * c;
    __syncthreads();
    const float* abase = &audio[((size_t)(b * SS + s0)) * 64];
    const float* vbase = &vision[((size_t)(b * SS + s0)) * 64];
#pragma unroll
    for (int r = 0; r < 8; ++r) {
      const int e = tid + 256 * r;
      sa[e >> 6][e & 63] = abase[e];
      sv[e >> 6][e & 63] = vbase[e];
    }
    if (tid < 32) swt[tid] = text[((size_t)(b * SS + s0 + tid)) * 128 + 127];
    __syncthreads();
    for (int s = 0; s < 32; ++s) {
      const float t = swt[s];
      float ar[4], vr[4];
#pragma unroll
      for (int i = 0; i < 4; ++i) ar[i] = sa[s][tv + 16 * i] * t;
#pragma unroll
      for (int j = 0; j < 4; ++j) vr[j] = sv[s][tw + 16 * j];
#pragma unroll
      for (int i = 0; i < 4; ++i)
#pragma unroll
        for (int j = 0; j < 4; ++j) acc[i][j] += ar[i] * vr[j];
    }
  }
  float ss = 0.f;
#pragma unroll
  for (int i = 0; i < 4; ++i) {
    const int a = 1 + tv + 16 * i;
    _Float16* Fb = Fh + (size_t)b * FPP + (size_t)a * APLANE;
#pragma unroll
    for (int j = 0; j < 4; ++j) {
      const int v = 1 + tw + 16 * j;
      float m = acc[i][j];
      ss += m * m;
      if (a == 64 && v == 64) { Flast[b] = m; m = 0.f; }  // exact fp32 path via k_final
      Fb[(size_t)v * VSTRIDE + 128] = (_Float16)m;
    }
  }
#pragma unroll
  for (int off = 32; off > 0; off >>= 1) ss += __shfl_down(ss, off);
  if ((tid & 63) == 0) atomicAdd(&normsq[b], ss);
}

// ---------------- deep-K MFMA GEMM v3: LDS-staged via global_load_lds, swizzled ----
// grid 1123 (padded-K split, KSP=512 -> 16 k32-steps). 4 waves; wave wv owns p-rows
// [32wv,32wv+32), all 128 b.
// sA[p][32k] f32: 16B slot s stored at s^(p&7)  (4-way ds_read_b128)
// sB[b][32k] f16: 16B slot s stored at s^(b&3)  (~8-way)
// gll dest is linear lane*size (HW rule); the XOR lives in the per-lane GLOBAL addr.
// One barrier per step: barrier -> issue next-step DMA -> compute current.
__global__ __launch_bounds__(256) void k_gemm(
    const float* __restrict__ W1, const _Float16* __restrict__ Fh,
    float* __restrict__ parts)
{
  __shared__ float    sA[2][4096];   // 2 x 16 KB
  __shared__ _Float16 sB[2][4096];   // 2 x 8 KB

  const int tid = threadIdx.x;
  const int wv = tid >> 6, ln = tid & 63;
  const int lb = ln & 31, hb = ln >> 5;
  const int p  = (wv << 5) + lb;
  const int kw = ln & 31;
  const int kp0 = blockIdx.x * KSP;

  // A-side per-lane W1-k trackers: variant j used by staging instrs n with n&3==j
  // (row parity class (2n+hb)&7). Advance +32/padded-step, skip 7 per VSTRIDE row.
  int wtr[4], kot[4];
#pragma unroll
  for (int j = 0; j < 4; ++j) {
    const int slog = (kw >> 2) ^ ((2 * j + hb) & 7);
    const int kp = kp0 + (slog << 2) + (kw & 3);
    const int a = kp / APLANE;
    const int rem = kp - a * APLANE;
    const int vv = rem / VSTRIDE;
    wtr[j] = rem - vv * VSTRIDE;
    kot[j] = kp - a * 455 - vv * 7;
  }

  // B-side per-lane source pointers (2 staging instrs cover rows 32wv..32wv+32)
  const int brow0 = (wv << 5) + (ln >> 2);
  const int slogB = (ln & 3) ^ ((ln >> 2) & 3);
  const _Float16* FhP0 = Fh + (size_t)brow0 * FPP + kp0 + (slogB << 3);
  const _Float16* FhP1 = FhP0 + (size_t)16 * FPP;

  const float* Wbase = W1 + (size_t)((wv << 5) + hb) * FUSED;

  f32x16 acc0 = {}, acc1 = {}, acc2 = {}, acc3 = {};

#define STAGE(BUF, KOFF)                                                        \
  {                                                                             \
    _Pragma("unroll")                                                           \
    for (int n = 0; n < 16; ++n) {                                              \
      const int kx = kot[n & 3];                                                \
      const int koc = (kx > 545024) ? 545024 : kx;                              \
      gll4(Wbase + (size_t)(2 * n) * FUSED + koc,                               \
           (char*)&sA[BUF][0] + (((wv << 5) + 2 * n) << 7));                    \
    }                                                                           \
    gll16(FhP0 + (KOFF), (char*)&sB[BUF][0] + ((wv << 5) << 6));                \
    gll16(FhP1 + (KOFF), (char*)&sB[BUF][0] + (((wv << 5) + 16) << 6));         \
    _Pragma("unroll")                                                           \
    for (int j = 0; j < 4; ++j) {                                               \
      wtr[j] += 32;                                                             \
      if (wtr[j] >= VSTRIDE) { wtr[j] -= VSTRIDE; kot[j] += 25; }               \
      else kot[j] += 32;                                                        \
    }                                                                           \
  }

  STAGE(0, 0)
  int buf = 0;
  for (int t = 0; t < 16; ++t) {
    __syncthreads();                     // drains the DMAs staged for `buf`
    if (t + 1 < 16) STAGE(buf ^ 1, (t + 1) * 32)
    const float* sAb = &sA[buf][0];
    const _Float16* sBb = &sB[buf][0];
#pragma unroll
    for (int ks = 0; ks < 2; ++ks) {
      const int s0 = (ks << 2) + (hb << 1);
      const float4 x0 = *(const float4*)((const char*)sAb + (p << 7) + (((s0)     ^ (p & 7)) << 4));
      const float4 x1 = *(const float4*)((const char*)sAb + (p << 7) + (((s0 + 1) ^ (p & 7)) << 4));
      half8 af;
      af[0] = (_Float16)x0.x; af[1] = (_Float16)x0.y;
      af[2] = (_Float16)x0.z; af[3] = (_Float16)x0.w;
      af[4] = (_Float16)x1.x; af[5] = (_Float16)x1.y;
      af[6] = (_Float16)x1.z; af[7] = (_Float16)x1.w;
      const char* bbase = (const char*)sBb + (lb << 6) +
                          (((((ks << 1) + hb) ^ (lb & 3))) << 4);
      const half8 b0 = *(const half8*)(bbase);
      const half8 b1 = *(const half8*)(bbase + 2048);
      const half8 b2 = *(const half8*)(bbase + 4096);
      const half8 b3 = *(const half8*)(bbase + 6144);
      acc0 = __builtin_amdgcn_mfma_f32_32x32x16_f16(af, b0, acc0, 0, 0, 0);
      acc1 = __builtin_amdgcn_mfma_f32_32x32x16_f16(af, b1, acc1, 0, 0, 0);
      acc2 = __builtin_amdgcn_mfma_f32_32x32x16_f16(af, b2, acc2, 0, 0, 0);
      acc3 = __builtin_amdgcn_mfma_f32_32x32x16_f16(af, b3, acc3, 0, 0, 0);
    }
    buf ^= 1;
  }
#undef STAGE

  // coalesced partial store: thread's 64 floats contiguous (same layout as before)
  f32x16* o = (f32x16*)(parts + ((size_t)blockIdx.x * 256 + tid) * 64);
  o[0] = acc0; o[1] = acc1; o[2] = acc2; o[3] = acc3;
}

// ---------------- reduce partials -> y1pre[b][p] ----------------
__global__ __launch_bounds__(256) void k_red(const float* __restrict__ parts,
                                             float* __restrict__ y1pre)
{
  const int tid = threadIdx.x;
  const int T = blockIdx.x * 4 + (tid >> 6);
  const int R = tid & 63;
  float s = 0.f;
  for (int sl = blockIdx.y; sl < NBLK; sl += 16)
    s += parts[(size_t)sl * 16384 + T * 64 + R];
  const int wv2 = T >> 6, hb2 = (T >> 5) & 1, lb2 = T & 31;
  const int q = R >> 4, rg = R & 15;
  const int b = q * 32 + lb2;
  const int pp = wv2 * 32 + (rg & 3) + 8 * (rg >> 2) + 4 * hb2;
  atomicAdd(&y1pre[b * PFD + pp], s);
}

// ---------------- finalize: MLP per batch ----------------
__global__ __launch_bounds__(128) void k_final(
    const float* __restrict__ y1pre, const float* __restrict__ b1,
    const float* __restrict__ W2, const float* __restrict__ b2,
    const float* __restrict__ W3, const float* __restrict__ b3,
    const float* __restrict__ W1, const float* __restrict__ Flast,
    float* __restrict__ out)
{
  const int b = blockIdx.x, p = threadIdx.x;
  __shared__ float y1[PFD];
  __shared__ float red[PFD];
  const float extra = W1[(size_t)p * FUSED + (FUSED - 1)] * Flast[b];
  y1[p] = fmaxf(y1pre[(size_t)b * PFD + p] + extra + b1[p], 0.f);
  __syncthreads();
  float s = b2[p];
  for (int k = 0; k < PFD; ++k) s += y1[k] * W2[p * PFD + k];
  const float y2 = fmaxf(s, 0.f);
  red[p] = y2 * W3[p];
  __syncthreads();
  for (int off = 64; off > 0; off >>= 1) {
    if (p < off) red[p] += red[p + off];
    __syncthreads();
  }
  if (p == 0) {
    const float x = red[0] + b3[0];
    out[b] = 6.f / (1.f + expf(-x)) - 3.f;
  }
}

__global__ __launch_bounds__(128) void k_reg(const float* __restrict__ normsq,
                                             float* __restrict__ out)
{
  const int t = threadIdx.x;
  __shared__ float red[BB];
  red[t] = sqrtf(normsq[t]);
  __syncthreads();
  for (int off = 64; off > 0; off >>= 1) {
    if (t < off) red[t] += red[t + off];
    __syncthreads();
  }
  // tmp = sqrt(64*64*128/128) = 64 exactly; mean over B
  if (t == 0) out[BB] = 64.f * red[0] / (float)BB;
}

extern "C" void kernel_launch(void* const* d_in, const int* in_sizes, int n_in,
                              void* d_out, int out_size, void* d_ws, size_t ws_size,
                              hipStream_t stream) {
  const float* audio  = (const float*)d_in[0];
  const float* vision = (const float*)d_in[1];
  const float* text   = (const float*)d_in[2];
  const float* W1     = (const float*)d_in[3];
  const float* b1     = (const float*)d_in[4];
  const float* W2     = (const float*)d_in[5];
  const float* b2     = (const float*)d_in[6];
  const float* W3     = (const float*)d_in[7];
  const float* b3     = (const float*)d_in[8];
  float* out = (float*)d_out;

  // ws layout (proven bound ws >= 279,183,872 B):
  // [y1pre 64KB][normsq][Flast] | Fh @131072 (147,193,856 B) |
  // parts @147,324,928 (1123*64KB = 73,596,928 B) -> total 220,921,856 B
  float* y1pre  = (float*)d_ws;
  float* normsq = y1pre + BB * PFD;
  float* Flast  = normsq + BB;
  _Float16* Fh  = (_Float16*)((char*)d_ws + 131072);
  float* parts  = (float*)((char*)d_ws + 147324928);

  k_zero<<<65, 256, 0, stream>>>(y1pre, BB * PFD + 2 * BB);
  k_fpad<<<BB, 256, 0, stream>>>(Fh);

  k_core<<<dim3(BB, 32), 256, 0, stream>>>(audio, vision, text, Fh, normsq);
  k_pa<<<BB, 256, 0, stream>>>(vision, text, Fh, normsq);
  k_pv<<<BB, 256, 0, stream>>>(audio, text, Fh, normsq);
  k_wlast<<<BB, 256, 0, stream>>>(audio, vision, text, Fh, Flast, normsq);

  k_gemm<<<NBLK, 256, 0, stream>>>(W1, Fh, parts);
  k_red<<<dim3(64, 16), 256, 0, stream>>>(parts, y1pre);

  k_final<<<BB, PFD, 0, stream>>>(y1pre, b1, W2, b2, W3, b3, W1, Flast, out);
  k_reg<<<1, BB, 0, stream>>>(normsq, out);
}

// Round 11
// 375.373 us; speedup vs baseline: 2.8626x; 1.3701x over previous
//
#include <hip/hip_runtime.h>
#include <math.h>

#define BB 128
#define SS 128
#define AE 65
#define VE 65
#define TE 129
#define PFD 128
#define FUSED 545025UL
#define FUSEDI 545025
#define VSTRIDE 136            // padded w-stride (multiple of 8)
#define APLANE 8840            // 65*136
#define FPP 574976UL           // padded per-b f16 k-extent = 512*1123
#define FPPI 574976
#define KSP 512
#define NBLK 1123              // FPPI / KSP

typedef _Float16 half8 __attribute__((ext_vector_type(8)));
typedef float f32x16 __attribute__((ext_vector_type(16)));

__device__ __forceinline__ void gll4(const void* g, void* l) {
  __builtin_amdgcn_global_load_lds((const __attribute__((address_space(1))) void*)g,
                                   (__attribute__((address_space(3))) void*)l, 4, 0, 0);
}
__device__ __forceinline__ void gll16(const void* g, void* l) {
  __builtin_amdgcn_global_load_lds((const __attribute__((address_space(1))) void*)g,
                                   (__attribute__((address_space(3))) void*)l, 16, 0, 0);
}

// ---------------- zero-init accumulators ----------------
__global__ __launch_bounds__(256) void k_zero(float* __restrict__ p, int n) {
  int i = blockIdx.x * 256 + threadIdx.x;
  if (i < n) p[i] = 0.f;
}

// zero the pad holes of Fh: per (b,a,v) w=129..135, plus per-b tail [574600,574976)
__global__ __launch_bounds__(256) void k_fpad(_Float16* __restrict__ Fh) {
  const int b = blockIdx.x;
  _Float16* base = Fh + (size_t)b * FPP;
  for (int i = threadIdx.x; i < 29575; i += 256) {   // 65*65*7
    const int a = i / 455, r = i - a * 455;
    const int v = r / 7, e = r - v * 7;
    base[a * APLANE + v * VSTRIDE + 129 + e] = (_Float16)0.f;
  }
  for (int i = threadIdx.x; i < 376; i += 256) base[574600 + i] = (_Float16)0.f;
}

// ---------------- core v3: MFMA, hi/lo-split operands (f32-exact fusion) ----------
// grid (BB, 8, 2): b, a-group (8 a), w-half (64 w). 256 thr = 4 waves.
// Per b: fusion = P @ T, P[(v),s] = a'[s]*v'[s,v] (A-op), T[s,w] (B-op).
// Split: P = Phi + Plo*2^-11, T = Thi + Tlo*2^-11 (lo stored prescaled by 2048
// to avoid f16 subnormals). acc += Phi*Thi ; accl += Plo*Thi + Phi*Tlo.
// fusion = acc + accl/2048  ->  ~f32-exact, same numerics as the old fp32 core.
__global__ __launch_bounds__(256) void k_core(
    const float* __restrict__ audio, const float* __restrict__ vision,
    const float* __restrict__ text, _Float16* __restrict__ Fh,
    float* __restrict__ normsq)
{
  const int b  = blockIdx.x;
  const int gy = blockIdx.y;          // a = 1+8gy .. 8+8gy
  const int gz = blockIdx.z;          // w = 64gz .. 64gz+63
  const int tid = threadIdx.x;
  const int wv = tid >> 6, ln = tid & 63;
  const int lr = ln & 31, hb = ln >> 5;

  __shared__ float    sVt[64][132];   // [v-1][s], 33 KB (row 528B = 33*16)
  __shared__ float    sAc[8][132];    // [j][s],   4.1 KB
  __shared__ _Float16 sTh[64][136];   // [w-local][s], 17 KB (row 272B = 17*16)
  __shared__ _Float16 sTl[64][136];   // prescaled *2048

  // ---- stage (once) ----
  {
    const float* vb = vision + (size_t)b * SS * 64;
#pragma unroll
    for (int r = 0; r < 32; ++r) {
      const int e = tid + 256 * r;    // 8192: s = e>>6, v = e&63 (coalesced read)
      sVt[e & 63][e >> 6] = vb[e];
    }
    const float* ab = audio + (size_t)b * SS * 64 + 8 * gy;
#pragma unroll
    for (int r = 0; r < 4; ++r) {
      const int e = tid + 256 * r;    // 1024: s = e>>3, j = e&7
      sAc[e & 7][e >> 3] = ab[(e >> 3) * 64 + (e & 7)];
    }
    const int wbase = 64 * gz;
    const float* tb = text + (size_t)b * SS * 128;
#pragma unroll
    for (int r = 0; r < 32; ++r) {
      const int e = tid + 256 * r;    // 8192: s = e>>6, wl = e&63
      const int s = e >> 6, wl = e & 63;
      const int w = wbase + wl;
      const float val = (w == 0) ? 1.f : tb[s * 128 + w - 1];
      const _Float16 th = (_Float16)val;
      sTh[wl][s] = th;
      sTl[wl][s] = (_Float16)((val - (float)th) * 2048.f);
    }
  }
  __syncthreads();

  float ss = 0.f;
  // 8 units per wave: u = 8wv+i -> rt = u>>1 (j = rt>>1, vh = rt&1), wt = u&1
  for (int i = 0; i < 8; ++i) {
    const int u  = 8 * wv + i;
    const int rt = u >> 1, wt = u & 1;
    const int j  = rt >> 1, vh = rt & 1;
    const int v0m = 32 * vh;          // v-1 base
    const int wl0 = 32 * wt;

    f32x16 acc = {}, accl = {};
#pragma unroll
    for (int ks = 0; ks < 8; ++ks) {
      const int s0 = 16 * ks + 8 * hb;
      const float4 x0 = *(const float4*)&sVt[v0m + lr][s0];
      const float4 x1 = *(const float4*)&sVt[v0m + lr][s0 + 4];
      const float4 a0 = *(const float4*)&sAc[j][s0];
      const float4 a1 = *(const float4*)&sAc[j][s0 + 4];
      const float pp[8] = {a0.x * x0.x, a0.y * x0.y, a0.z * x0.z, a0.w * x0.w,
                           a1.x * x1.x, a1.y * x1.y, a1.z * x1.z, a1.w * x1.w};
      half8 afh, afl;
#pragma unroll
      for (int e = 0; e < 8; ++e) {
        const _Float16 h = (_Float16)pp[e];
        afh[e] = h;
        afl[e] = (_Float16)((pp[e] - (float)h) * 2048.f);
      }
      const half8 bqh = *(const half8*)&sTh[wl0 + lr][s0];
      const half8 bql = *(const half8*)&sTl[wl0 + lr][s0];
      acc  = __builtin_amdgcn_mfma_f32_32x32x16_f16(afh, bqh, acc,  0, 0, 0);
      accl = __builtin_amdgcn_mfma_f32_32x32x16_f16(afl, bqh, accl, 0, 0, 0);
      accl = __builtin_amdgcn_mfma_f32_32x32x16_f16(afh, bql, accl, 0, 0, 0);
    }

    const int a = 1 + 8 * gy + j;
    _Float16* Fb = Fh + (size_t)b * FPP + (size_t)a * APLANE;
    const int wg = 64 * gz + wl0 + lr;          // this lane's w column (C col)
#pragma unroll
    for (int reg = 0; reg < 16; ++reg) {
      const int crow = (reg & 3) + 8 * (reg >> 2) + 4 * hb;
      const int v = 1 + 32 * vh + crow;
      const float f = acc[reg] + accl[reg] * (1.f / 2048.f);
      ss += f * f;
      Fb[(size_t)v * VSTRIDE + wg] = (_Float16)f;
    }
  }

#pragma unroll
  for (int off = 32; off > 0; off >>= 1) ss += __shfl_down(ss, off);
  if (ln == 0) atomicAdd(&normsq[b], ss);
}

// ---------------- plane a=0: v 0..64, w 0..128 ----------------
__global__ __launch_bounds__(256) void k_pa(
    const float* __restrict__ vision, const float* __restrict__ text,
    _Float16* __restrict__ Fh, float* __restrict__ normsq)
{
  const int b = blockIdx.x;
  const int tid = threadIdx.x;
  const int tw = tid & 15, tv = tid >> 4;
  __shared__ float sv[32][80];
  __shared__ float st[32][144];
  float acc[5][9];
#pragma unroll
  for (int i = 0; i < 5; ++i)
#pragma unroll
    for (int j = 0; j < 9; ++j) acc[i][j] = 0.f;

  for (int c = 0; c < 4; ++c) {
    const int s0 = 32 * c;
    __syncthreads();
    const float* vbase = &vision[((size_t)(b * SS + s0)) * 64];
#pragma unroll
    for (int r = 0; r < 8; ++r) {
      const int e = tid + 256 * r;
      sv[e >> 6][(e & 63) + 1] = vbase[e];
    }
    const float* tbase = &text[((size_t)(b * SS + s0)) * 128];
#pragma unroll
    for (int r = 0; r < 16; ++r) {
      const int e = tid + 256 * r;
      st[e >> 7][(e & 127) + 1] = tbase[e];
    }
    if (tid < 32) { sv[tid][0] = 1.f; st[tid][0] = 1.f; }
    __syncthreads();
    for (int s = 0; s < 32; ++s) {
      float vr[5], tr[9];
#pragma unroll
      for (int i = 0; i < 5; ++i) {
        const int vx = tv + 16 * i;
        vr[i] = (vx < VE) ? sv[s][vx] : 0.f;
      }
#pragma unroll
      for (int j = 0; j < 9; ++j) {
        const int wx = tw + 16 * j;
        tr[j] = (wx < TE) ? st[s][wx] : 0.f;
      }
#pragma unroll
      for (int i = 0; i < 5; ++i)
#pragma unroll
        for (int j = 0; j < 9; ++j) acc[i][j] += vr[i] * tr[j];
    }
  }
  _Float16* Fb = Fh + (size_t)b * FPP;   // a = 0
  float ss = 0.f;
#pragma unroll
  for (int i = 0; i < 5; ++i) {
    const int v = tv + 16 * i;
    if (v < VE) {
#pragma unroll
      for (int j = 0; j < 9; ++j) {
        const int w = tw + 16 * j;
        if (w < TE) {
          const float m = acc[i][j];
          Fb[(size_t)v * VSTRIDE + w] = (_Float16)m;
          ss += m * m;
        }
      }
    }
  }
#pragma unroll
  for (int off = 32; off > 0; off >>= 1) ss += __shfl_down(ss, off);
  if ((tid & 63) == 0) atomicAdd(&normsq[b], ss);
}

// ---------------- plane v=0: a 1..64, w 0..128 ----------------
__global__ __launch_bounds__(256) void k_pv(
    const float* __restrict__ audio, const float* __restrict__ text,
    _Float16* __restrict__ Fh, float* __restrict__ normsq)
{
  const int b = blockIdx.x;
  const int tid = threadIdx.x;
  const int tw = tid & 15, tv = tid >> 4;
  __shared__ float sa[32][64];
  __shared__ float st[32][144];
  float acc[4][9];
#pragma unroll
  for (int i = 0; i < 4; ++i)
#pragma unroll
    for (int j = 0; j < 9; ++j) acc[i][j] = 0.f;

  for (int c = 0; c < 4; ++c) {
    const int s0 = 32 * c;
    __syncthreads();
    const float* abase = &audio[((size_t)(b * SS + s0)) * 64];
#pragma unroll
    for (int r = 0; r < 8; ++r) {
      const int e = tid + 256 * r;
      sa[e >> 6][e & 63] = abase[e];
    }
    const float* tbase = &text[((size_t)(b * SS + s0)) * 128];
#pragma unroll
    for (int r = 0; r < 16; ++r) {
      const int e = tid + 256 * r;
      st[e >> 7][(e & 127) + 1] = tbase[e];
    }
    if (tid < 32) st[tid][0] = 1.f;
    __syncthreads();
    for (int s = 0; s < 32; ++s) {
      float ar[4], tr[9];
#pragma unroll
      for (int i = 0; i < 4; ++i) ar[i] = sa[s][tv + 16 * i];
#pragma unroll
      for (int j = 0; j < 9; ++j) {
        const int wx = tw + 16 * j;
        tr[j] = (wx < TE) ? st[s][wx] : 0.f;
      }
#pragma unroll
      for (int i = 0; i < 4; ++i)
#pragma unroll
        for (int j = 0; j < 9; ++j) acc[i][j] += ar[i] * tr[j];
    }
  }
  float ss = 0.f;
#pragma unroll
  for (int i = 0; i < 4; ++i) {
    const int a = 1 + tv + 16 * i;
    _Float16* Fb = Fh + (size_t)b * FPP + (size_t)a * APLANE;   // v = 0
#pragma unroll
    for (int j = 0; j < 9; ++j) {
      const int w = tw + 16 * j;
      if (w < TE) {
        const float m = acc[i][j];
        Fb[w] = (_Float16)m;
        ss += m * m;
      }
    }
  }
#pragma unroll
  for (int off = 32; off > 0; off >>= 1) ss += __shfl_down(ss, off);
  if ((tid & 63) == 0) atomicAdd(&normsq[b], ss);
}

// ---------------- column w=128: a 1..64, v 1..64 ----------------
__global__ __launch_bounds__(256) void k_wlast(
    const float* __restrict__ audio, const float* __restrict__ vision,
    const float* __restrict__ text, _Float16* __restrict__ Fh,
    float* __restrict__ Flast, float* __restrict__ normsq)
{
  const int b = blockIdx.x;
  const int tid = threadIdx.x;
  const int tw = tid & 15, tv = tid >> 4;
  __shared__ float sa[32][64];
  __shared__ float sv[32][64];
  __shared__ float swt[32];
  float acc[4][4];
#pragma unroll
  for (int i = 0; i < 4; ++i)
#pragma unroll
    for (int j = 0; j < 4; ++j) acc[i][j] = 0.f;

  for (int c = 0; c < 4; ++c) {
    const int s0 = 32 * c;
    __syncthreads();
    const float* abase = &audio[((size_t)(b * SS + s0)) * 64];
    const float* vbase = &vision[((size_t)(b * SS + s0)) * 64];
#pragma unroll
    for (int r = 0; r < 8; ++r) {
      const int e = tid + 256 * r;
      sa[e >> 6][e & 63] = abase[e];
      sv[e >> 6][e & 63] = vbase[e];
    }
    if (tid < 32) swt[tid] = text[((size_t)(b * SS + s0 + tid)) * 128 + 127];
    __syncthreads();
    for (int s = 0; s < 32; ++s) {
      const float t = swt[s];
      float ar[4], vr[4];
#pragma unroll
      for (int i = 0; i < 4; ++i) ar[i] = sa[s][tv + 16 * i] * t;
#pragma unroll
      for (int j = 0; j < 4; ++j) vr[j] = sv[s][tw + 16 * j];
#pragma unroll
      for (int i = 0; i < 4; ++i)
#pragma unroll
        for (int j = 0; j < 4; ++j) acc[i][j] += ar[i] * vr[j];
    }
  }
  float ss = 0.f;
#pragma unroll
  for (int i = 0; i < 4; ++i) {
    const int a = 1 + tv + 16 * i;
    _Float16* Fb = Fh + (size_t)b * FPP + (size_t)a * APLANE;
#pragma unroll
    for (int j = 0; j < 4; ++j) {
      const int v = 1 + tw + 16 * j;
      float m = acc[i][j];
      ss += m * m;
      if (a == 64 && v == 64) { Flast[b] = m; m = 0.f; }  // exact fp32 path via k_final
      Fb[(size_t)v * VSTRIDE + 128] = (_Float16)m;
    }
  }
#pragma unroll
  for (int off = 32; off > 0; off >>= 1) ss += __shfl_down(ss, off);
  if ((tid & 63) == 0) atomicAdd(&normsq[b], ss);
}

// ---------------- deep-K MFMA GEMM v3: LDS-staged via global_load_lds, swizzled ----
__global__ __launch_bounds__(256) void k_gemm(
    const float* __restrict__ W1, const _Float16* __restrict__ Fh,
    float* __restrict__ parts)
{
  __shared__ float    sA[2][4096];   // 2 x 16 KB
  __shared__ _Float16 sB[2][4096];   // 2 x 8 KB

  const int tid = threadIdx.x;
  const int wv = tid >> 6, ln = tid & 63;
  const int lb = ln & 31, hb = ln >> 5;
  const int p  = (wv << 5) + lb;
  const int kw = ln & 31;
  const int kp0 = blockIdx.x * KSP;

  int wtr[4], kot[4];
#pragma unroll
  for (int j = 0; j < 4; ++j) {
    const int slog = (kw >> 2) ^ ((2 * j + hb) & 7);
    const int kp = kp0 + (slog << 2) + (kw & 3);
    const int a = kp / APLANE;
    const int rem = kp - a * APLANE;
    const int vv = rem / VSTRIDE;
    wtr[j] = rem - vv * VSTRIDE;
    kot[j] = kp - a * 455 - vv * 7;
  }

  const int brow0 = (wv << 5) + (ln >> 2);
  const int slogB = (ln & 3) ^ ((ln >> 2) & 3);
  const _Float16* FhP0 = Fh + (size_t)brow0 * FPP + kp0 + (slogB << 3);
  const _Float16* FhP1 = FhP0 + (size_t)16 * FPP;

  const float* Wbase = W1 + (size_t)((wv << 5) + hb) * FUSED;

  f32x16 acc0 = {}, acc1 = {}, acc2 = {}, acc3 = {};

#define STAGE(BUF, KOFF)                                                        \
  {                                                                             \
    _Pragma("unroll")                                                           \
    for (int n = 0; n < 16; ++n) {                                              \
      const int kx = kot[n & 3];                                                \
      const int koc = (kx > 545024) ? 545024 : kx;                              \
      gll4(Wbase + (size_t)(2 * n) * FUSED + koc,                               \
           (char*)&sA[BUF][0] + (((wv << 5) + 2 * n) << 7));                    \
    }                                                                           \
    gll16(FhP0 + (KOFF), (char*)&sB[BUF][0] + ((wv << 5) << 6));                \
    gll16(FhP1 + (KOFF), (char*)&sB[BUF][0] + (((wv << 5) + 16) << 6));         \
    _Pragma("unroll")                                                           \
    for (int j = 0; j < 4; ++j) {                                               \
      wtr[j] += 32;                                                             \
      if (wtr[j] >= VSTRIDE) { wtr[j] -= VSTRIDE; kot[j] += 25; }               \
      else kot[j] += 32;                                                        \
    }                                                                           \
  }

  STAGE(0, 0)
  int buf = 0;
  for (int t = 0; t < 16; ++t) {
    __syncthreads();                     // drains the DMAs staged for `buf`
    if (t + 1 < 16) STAGE(buf ^ 1, (t + 1) * 32)
    const float* sAb = &sA[buf][0];
    const _Float16* sBb = &sB[buf][0];
#pragma unroll
    for (int ks = 0; ks < 2; ++ks) {
      const int s0 = (ks << 2) + (hb << 1);
      const float4 x0 = *(const float4*)((const char*)sAb + (p << 7) + (((s0)     ^ (p & 7)) << 4));
      const float4 x1 = *(const float4*)((const char*)sAb + (p << 7) + (((s0 + 1) ^ (p & 7)) << 4));
      half8 af;
      af[0] = (_Float16)x0.x; af[1] = (_Float16)x0.y;
      af[2] = (_Float16)x0.z; af[3] = (_Float16)x0.w;
      af[4] = (_Float16)x1.x; af[5] = (_Float16)x1.y;
      af[6] = (_Float16)x1.z; af[7] = (_Float16)x1.w;
      const char* bbase = (const char*)sBb + (lb << 6) +
                          (((((ks << 1) + hb) ^ (lb & 3))) << 4);
      const half8 b0 = *(const half8*)(bbase);
      const half8 b1 = *(const half8*)(bbase + 2048);
      const half8 b2 = *(const half8*)(bbase + 4096);
      const half8 b3 = *(const half8*)(bbase + 6144);
      acc0 = __builtin_amdgcn_mfma_f32_32x32x16_f16(af, b0, acc0, 0, 0, 0);
      acc1 = __builtin_amdgcn_mfma_f32_32x32x16_f16(af, b1, acc1, 0, 0, 0);
      acc2 = __builtin_amdgcn_mfma_f32_32x32x16_f16(af, b2, acc2, 0, 0, 0);
      acc3 = __builtin_amdgcn_mfma_f32_32x32x16_f16(af, b3, acc3, 0, 0, 0);
    }
    buf ^= 1;
  }
#undef STAGE

  f32x16* o = (f32x16*)(parts + ((size_t)blockIdx.x * 256 + tid) * 64);
  o[0] = acc0; o[1] = acc1; o[2] = acc2; o[3] = acc3;
}

// ---------------- reduce partials -> y1pre[b][p] ----------------
__global__ __launch_bounds__(256) void k_red(const float* __restrict__ parts,
                                             float* __restrict__ y1pre)
{
  const int tid = threadIdx.x;
  const int T = blockIdx.x * 4 + (tid >> 6);
  const int R = tid & 63;
  float s = 0.f;
  for (int sl = blockIdx.y; sl < NBLK; sl += 16)
    s += parts[(size_t)sl * 16384 + T * 64 + R];
  const int wv2 = T >> 6, hb2 = (T >> 5) & 1, lb2 = T & 31;
  const int q = R >> 4, rg = R & 15;
  const int b = q * 32 + lb2;
  const int pp = wv2 * 32 + (rg & 3) + 8 * (rg >> 2) + 4 * hb2;
  atomicAdd(&y1pre[b * PFD + pp], s);
}

// ---------------- finalize: MLP per batch ----------------
__global__ __launch_bounds__(128) void k_final(
    const float* __restrict__ y1pre, const float* __restrict__ b1,
    const float* __restrict__ W2, const float* __restrict__ b2,
    const float* __restrict__ W3, const float* __restrict__ b3,
    const float* __restrict__ W1, const float* __restrict__ Flast,
    float* __restrict__ out)
{
  const int b = blockIdx.x, p = threadIdx.x;
  __shared__ float y1[PFD];
  __shared__ float red[PFD];
  const float extra = W1[(size_t)p * FUSED + (FUSED - 1)] * Flast[b];
  y1[p] = fmaxf(y1pre[(size_t)b * PFD + p] + extra + b1[p], 0.f);
  __syncthreads();
  float s = b2[p];
  for (int k = 0; k < PFD; ++k) s += y1[k] * W2[p * PFD + k];
  const float y2 = fmaxf(s, 0.f);
  red[p] = y2 * W3[p];
  __syncthreads();
  for (int off = 64; off > 0; off >>= 1) {
    if (p < off) red[p] += red[p + off];
    __syncthreads();
  }
  if (p == 0) {
    const float x = red[0] + b3[0];
    out[b] = 6.f / (1.f + expf(-x)) - 3.f;
  }
}

__global__ __launch_bounds__(128) void k_reg(const float* __restrict__ normsq,
                                             float* __restrict__ out)
{
  const int t = threadIdx.x;
  __shared__ float red[BB];
  red[t] = sqrtf(normsq[t]);
  __syncthreads();
  for (int off = 64; off > 0; off >>= 1) {
    if (t < off) red[t] += red[t + off];
    __syncthreads();
  }
  // tmp = sqrt(64*64*128/128) = 64 exactly; mean over B
  if (t == 0) out[BB] = 64.f * red[0] / (float)BB;
}

extern "C" void kernel_launch(void* const* d_in, const int* in_sizes, int n_in,
                              void* d_out, int out_size, void* d_ws, size_t ws_size,
                              hipStream_t stream) {
  const float* audio  = (const float*)d_in[0];
  const float* vision = (const float*)d_in[1];
  const float* text   = (const float*)d_in[2];
  const float* W1     = (const float*)d_in[3];
  const float* b1     = (const float*)d_in[4];
  const float* W2     = (const float*)d_in[5];
  const float* b2     = (const float*)d_in[6];
  const float* W3     = (const float*)d_in[7];
  const float* b3     = (const float*)d_in[8];
  float* out = (float*)d_out;

  // ws layout (proven bound ws >= 279,183,872 B):
  // [y1pre 64KB][normsq][Flast] | Fh @131072 (147,193,856 B) |
  // parts @147,324,928 (1123*64KB = 73,596,928 B) -> total 220,921,856 B
  float* y1pre  = (float*)d_ws;
  float* normsq = y1pre + BB * PFD;
  float* Flast  = normsq + BB;
  _Float16* Fh  = (_Float16*)((char*)d_ws + 131072);
  float* parts  = (float*)((char*)d_ws + 147324928);

  k_zero<<<65, 256, 0, stream>>>(y1pre, BB * PFD + 2 * BB);
  k_fpad<<<BB, 256, 0, stream>>>(Fh);

  k_core<<<dim3(BB, 8, 2), 256, 0, stream>>>(audio, vision, text, Fh, normsq);
  k_pa<<<BB, 256, 0, stream>>>(vision, text, Fh, normsq);
  k_pv<<<BB, 256, 0, stream>>>(audio, text, Fh, normsq);
  k_wlast<<<BB, 256, 0, stream>>>(audio, vision, text, Fh, Flast, normsq);

  k_gemm<<<NBLK, 256, 0, stream>>>(W1, Fh, parts);
  k_red<<<dim3(64, 16), 256, 0, stream>>>(parts, y1pre);

  k_final<<<BB, PFD, 0, stream>>>(y1pre, b1, W2, b2, W3, b3, W1, Flast, out);
  k_reg<<<1, BB, 0, stream>>>(normsq, out);
}